// Round 3
// baseline (773.674 us; speedup 1.0000x reference)
//
#include <hip/hip_runtime.h>

// APPNP block: 10 hops of symmetric-normalized propagation + FFN + residual.
// Round 11: agg path unchanged (R6 fused lockstep, ~38us/hop).
// BUILD v3: Phase A (single edge scan -> 8x64 compact sub-streams via
// ballot-aggregated appends) kept from R10. Phase B REWRITTEN: the scatter
// version paid 90MB WRITE (every 2B ELL store = dirty-line writeback,
// VALUBusy 0.7%, 125us). Now 400 XCD-pinned blocks (8 partitions x 50
// windows of 250 nodes) each scan their partition's compact bins from L2,
// accumulate their window's ELL rows + counts entirely in LDS (52KB, LDS
// atomics), then write the slice back with coalesced uint4 stores. cnt4 is
// written wholesale (no pre-zero needed).
// FFN (R10): 4 thr/node, h tile in LDS stride 49, weights via wave-uniform
// scalar loads from global.

constexpr int N      = 100000;
constexpr int E      = 1600000;
constexpr int D      = 48;     // floats per node
constexpr int D4     = 12;     // float4 per node
constexpr int C8     = 6;      // chunks of 8 bf16 (16B) per node
constexpr int HALF   = N * C8 / 2;   // 300000 threads, 2 (n,c) pairs each
constexpr int NB     = 4;      // source buckets, width 25000
constexpr int BW     = 25000;  // bucket width (fits ushort local ids)
constexpr int BCAP   = 24;     // per-(node,bucket) cap; P(Bin(deg,1/4)>24) ~ 1e-8
constexpr int FNB    = 64;     // ffn nodes per block (256 thr = 64 nodes x 4 chunks)
constexpr int HP     = 49;     // padded LDS row stride (odd -> bank-conflict-free)
constexpr int NPART  = 8;      // dst partitions (one per XCD)
constexpr int PW     = 12500;  // partition width
constexpr int SUBS   = 64;     // sub-streams per partition
constexpr int SUBCAP = 4096;   // uints per sub-stream (mean 3125, sd ~56 -> 17 sd)
constexpr int TSTR   = 16;     // ints per tail slot (64B line -> no line contention)
constexpr int WNODES = 250;    // nodes per build window (50 windows/partition)
constexpr int NWIN   = PW / WNODES;  // 50

typedef unsigned int uint;
typedef unsigned short ushort_t;
typedef uint  __attribute__((ext_vector_type(4))) nuint4;
typedef float __attribute__((ext_vector_type(4))) nfloat4;

__device__ __forceinline__ uint pack_bf16x2(float x, float y) {
    uint bx = __float_as_uint(x), by = __float_as_uint(y);
    bx = (bx + 0x7FFFu + ((bx >> 16) & 1u)) >> 16;          // RNE
    by = (by + 0x7FFFu + ((by >> 16) & 1u)) >> 16;
    return bx | (by << 16);
}

__device__ __forceinline__ void unpack_add(uint u, float& a0, float& a1) {
    a0 += __uint_as_float(u << 16);
    a1 += __uint_as_float(u & 0xFFFF0000u);
}

__global__ __launch_bounds__(256) void zero_kernel(int* __restrict__ tails) {
    int i = blockIdx.x * 256 + threadIdx.x;
    if (i < NPART * SUBS * TSTR) tails[i] = 0;
}

// Phase A: single scan of the edge list. 4 edges/thread via int4. Each edge
// packed to one uint and appended to sub-stream (p, sub) with ONE global
// atomic per wave per partition (ballot aggregation). Group members write
// consecutive slots -> coalesced segments.
__global__ __launch_bounds__(256) void bin_scan_kernel(const int* __restrict__ src,
                                                       const int* __restrict__ dst,
                                                       uint* __restrict__ bins,
                                                       int* __restrict__ tails) {
    int t = blockIdx.x * 256 + threadIdx.x;
    int e0 = t * 4;
    if (e0 >= E) return;                       // E%1024==0 per-wave uniform
    int lane = threadIdx.x & 63;
    int sub = ((uint)t >> 6) & (SUBS - 1);     // wave-uniform stream id
    int4 dv = *(const int4*)(dst + e0);
    int4 sv = *(const int4*)(src + e0);
#pragma unroll
    for (int r = 0; r < 4; ++r) {
        int d = r == 0 ? dv.x : (r == 1 ? dv.y : (r == 2 ? dv.z : dv.w));
        int s = r == 0 ? sv.x : (r == 1 ? sv.y : (r == 2 ? sv.z : sv.w));
        uint p = (uint)d / (uint)PW;           // 0..7 (magic mul)
        uint pk = (uint)(d - (int)p * PW) | ((uint)s << 14);
#pragma unroll
        for (uint pp = 0; pp < NPART; ++pp) {
            unsigned long long m = __ballot(p == pp);
            if (m == 0ull) continue;           // wave-uniform
            int cnt = __popcll(m);
            int base = 0;
            if (lane == 0) base = atomicAdd(&tails[(pp * SUBS + sub) * TSTR], cnt);
            base = __shfl(base, 0);
            if (p == pp) {
                int before = __popcll(m & ((1ull << lane) - 1ull));
                int pos = base + before;
                if (pos < SUBCAP)
                    bins[((pp * SUBS + sub) << 12) + pos] = pk;
            }
        }
    }
}

// Phase B: window build. Block (p = blockIdx&7 -> XCD-pinned, w = blockIdx>>3)
// scans partition p's compact sub-streams (800KB, L2-resident, shared by the
// 50 sibling blocks on the same XCD), keeps edges whose dst falls in its
// 250-node window, accumulates ELL rows + counts in LDS (LDS atomics), then
// writes the whole slice back with coalesced uint4 stores (full-line writes,
// no write amplification, no global atomics).
__global__ __launch_bounds__(256) void build_window_kernel(const uint* __restrict__ bins,
                                                           const int* __restrict__ tails,
                                                           int* __restrict__ cnt4,
                                                           ushort_t* __restrict__ ell16) {
    __shared__ int lcnt[WNODES * NB];                       //  4000 B
    __shared__ __align__(16) ushort_t lell[WNODES * NB * BCAP];  // 48000 B

    int p   = blockIdx.x & 7;
    int w   = blockIdx.x >> 3;
    int wlo = w * WNODES;                   // window base, partition-local
    int tid = threadIdx.x;

    for (int i = tid; i < WNODES * NB; i += 256) lcnt[i] = 0;
    __syncthreads();

    for (int ss = 0; ss < SUBS; ++ss) {
        int cnt = tails[(p * SUBS + ss) * TSTR];
        if (cnt > SUBCAP) cnt = SUBCAP;
        const uint* bs = bins + ((p * SUBS + ss) << 12);
        for (int i = tid; i < cnt; i += 256) {
            uint u = bs[i];
            int dl = (int)(u & 0x3FFFu) - wlo;
            if ((uint)dl < (uint)WNODES) {
                int s = (int)(u >> 14);
                int b = (s >= BW) + (s >= 2 * BW) + (s >= 3 * BW);
                int lidx = dl * NB + b;
                int cpos = atomicAdd(&lcnt[lidx], 1);
                if (cpos < BCAP) lell[lidx * BCAP + cpos] = (ushort_t)(s - b * BW);
            }
        }
    }
    __syncthreads();

    int nbase = p * PW + wlo;
    int* gcnt = cnt4 + (size_t)nbase * NB;
    for (int i = tid; i < WNODES * NB; i += 256) gcnt[i] = lcnt[i];
    const uint4* l4 = (const uint4*)lell;
    uint4* g4 = (uint4*)(ell16 + (size_t)nbase * NB * BCAP);
    constexpr int NV4 = WNODES * NB * BCAP * 2 / 16;        // 3000
    for (int i = tid; i < NV4; i += 256)
        __builtin_nontemporal_store(*(const nuint4*)&l4[i], (nuint4*)&g4[i]);
}

// scaled0 = feat*norm (bf16, node-major 96B rows) and h0s = 0.1*feat (bf16).
// True in-degree = raw sum of the 4 bucket counters (cap only limits gathers).
__global__ __launch_bounds__(256) void norm_scaled0_kernel(const int* __restrict__ cnt4,
                                                           const float4* __restrict__ feat,
                                                           float* __restrict__ norm,
                                                           uint4* __restrict__ sA,
                                                           uint4* __restrict__ h0s) {
    int t = blockIdx.x * 256 + threadIdx.x;
    if (t >= N * C8) return;
    int n = t / C8;
    int c = t - n * C8;
    int4 cc = *(const int4*)(cnt4 + n * NB);
    float dg = (float)(cc.x + cc.y + cc.z + cc.w);
    float nm = 1.0f / sqrtf(fmaxf(dg, 1.0f));
    if (c == 0) norm[n] = nm;
    float4 v0 = feat[n * D4 + c * 2];
    float4 v1 = feat[n * D4 + c * 2 + 1];
    uint4 o;
    o.x = pack_bf16x2(v0.x * nm, v0.y * nm);
    o.y = pack_bf16x2(v0.z * nm, v0.w * nm);
    o.z = pack_bf16x2(v1.x * nm, v1.y * nm);
    o.w = pack_bf16x2(v1.z * nm, v1.w * nm);
    sA[t] = o;
    uint4 h;
    h.x = pack_bf16x2(v0.x * 0.1f, v0.y * 0.1f);
    h.y = pack_bf16x2(v0.z * 0.1f, v0.w * 0.1f);
    h.z = pack_bf16x2(v1.x * 0.1f, v1.y * 0.1f);
    h.w = pack_bf16x2(v1.z * 0.1f, v1.w * 0.1f);
    h0s[t] = h;
}

// Fused lockstep agg (R6): thread i owns (n0=i/6, c) and (n1=n0+50000, c).
// Bucket loop outermost; grid 1172 blocks = 4688 waves, fully co-resident.
// 6 consecutive lanes read one source node's contiguous 96B bf16 row.
template <bool LAST>
__global__ __launch_bounds__(256) void agg_kernel(const uint4* __restrict__ scaled_in,
                                                  const ushort_t* __restrict__ ell16,
                                                  const int* __restrict__ cnt4,
                                                  const float* __restrict__ norm,
                                                  const uint4* __restrict__ h0s,
                                                  uint4* __restrict__ scaled_out,
                                                  float4* __restrict__ h_out) {
    int i = blockIdx.x * 256 + threadIdx.x;
    if (i >= HALF) return;
    int n0 = i / C8;
    int c  = i - n0 * C8;
    int n1 = n0 + N / 2;
    int t0 = i, t1 = i + HALF;

    int4 cc0 = *(const int4*)(cnt4 + n0 * NB);
    int4 cc1 = *(const int4*)(cnt4 + n1 * NB);
    int cb0[NB] = {min(cc0.x, BCAP), min(cc0.y, BCAP), min(cc0.z, BCAP), min(cc0.w, BCAP)};
    int cb1[NB] = {min(cc1.x, BCAP), min(cc1.y, BCAP), min(cc1.z, BCAP), min(cc1.w, BCAP)};
    float nm0 = norm[n0], nm1 = norm[n1];
    const ushort_t* r0 = ell16 + (size_t)n0 * (NB * BCAP);
    const ushort_t* r1 = ell16 + (size_t)n1 * (NB * BCAP);

    float a0[8] = {0.f, 0.f, 0.f, 0.f, 0.f, 0.f, 0.f, 0.f};
    float a1[8] = {0.f, 0.f, 0.f, 0.f, 0.f, 0.f, 0.f, 0.f};

    auto addv = [](uint4 v, float* a) {
        unpack_add(v.x, a[0], a[1]); unpack_add(v.y, a[2], a[3]);
        unpack_add(v.z, a[4], a[5]); unpack_add(v.w, a[6], a[7]);
    };
    auto run = [&](const ushort_t* row, int cnt, const uint4* base, float* a) {
        int j = 0;
        for (; j + 4 <= cnt; j += 4) {
            int s0 = row[j], s1 = row[j + 1], s2 = row[j + 2], s3 = row[j + 3];
            uint4 v0 = base[s0 * C8];
            uint4 v1 = base[s1 * C8];
            uint4 v2 = base[s2 * C8];
            uint4 v3 = base[s3 * C8];
            addv(v0, a); addv(v1, a); addv(v2, a); addv(v3, a);
        }
        for (; j < cnt; ++j) {
            uint4 v = base[row[j] * C8];
            addv(v, a);
        }
    };

#pragma unroll
    for (int p = 0; p < NB; ++p) {
        const uint4* base = scaled_in + (size_t)p * (BW * C8) + c;
        run(r0 + p * BCAP, cb0[p], base, a0);
        run(r1 + p * BCAP, cb1[p], base, a1);
    }

    auto finish = [&](int t, int n, float nm, float* a) {
        nuint4 hs = __builtin_nontemporal_load((const nuint4*)&h0s[t]);
        float rr[8] = {0.f, 0.f, 0.f, 0.f, 0.f, 0.f, 0.f, 0.f};
        unpack_add(hs.x, rr[0], rr[1]); unpack_add(hs.y, rr[2], rr[3]);
        unpack_add(hs.z, rr[4], rr[5]); unpack_add(hs.w, rr[6], rr[7]);
        float s = 0.9f * nm;
        float hv[8];
#pragma unroll
        for (int k = 0; k < 8; ++k) hv[k] = fmaf(s, a[k], rr[k]);
        if (LAST) {
            nfloat4 o0 = {hv[0], hv[1], hv[2], hv[3]};
            nfloat4 o1 = {hv[4], hv[5], hv[6], hv[7]};
            __builtin_nontemporal_store(o0, (nfloat4*)&h_out[n * D4 + c * 2]);
            __builtin_nontemporal_store(o1, (nfloat4*)&h_out[n * D4 + c * 2 + 1]);
        } else {
            nuint4 o;
            o.x = pack_bf16x2(hv[0] * nm, hv[1] * nm);
            o.y = pack_bf16x2(hv[2] * nm, hv[3] * nm);
            o.z = pack_bf16x2(hv[4] * nm, hv[5] * nm);
            o.w = pack_bf16x2(hv[6] * nm, hv[7] * nm);
            __builtin_nontemporal_store(o, (nuint4*)&scaled_out[t]);
        }
    };
    finish(t0, n0, nm0, a0);
    finish(t1, n1, nm1, a1);
}

// rst = relu(h@w1 + b1)@w2 + b2 + features.
// 4 threads per node (chunk = tid>>6 owns 12 outputs), 64 nodes per block.
// h row staged in LDS stride 49 (free 2-way bank alias on scalar reads);
// hid reuses the same buffer between barriers. Weights/biases are read with
// wave-uniform SCALAR loads from global (co = readfirstlane, uniform control
// flow; only the final store is guarded) -> no DS-pipe cost for weights.
__global__ __launch_bounds__(256) void ffn_kernel(const float* __restrict__ r,
                                                  const float* __restrict__ feat,
                                                  const float* __restrict__ w1,
                                                  const float* __restrict__ b1,
                                                  const float* __restrict__ w2,
                                                  const float* __restrict__ b2,
                                                  float* __restrict__ rst) {
    __shared__ float sh[FNB * HP];      // h tile, reused for hid

    int tid = threadIdx.x;
    int nb = blockIdx.x * FNB;
    // stage h rows: up to 64 rows x 12 float4, coalesced global reads
    const float4* r4 = (const float4*)r + (size_t)nb * D4;
    int maxf4 = (N - nb) * D4;
    if (maxf4 > FNB * D4) maxf4 = FNB * D4;
    for (int f = tid; f < maxf4; f += 256) {
        float4 v = r4[f];
        int row = f / D4;
        int col = (f - row * D4) * 4;
        float* dp = sh + row * HP + col;
        dp[0] = v.x; dp[1] = v.y; dp[2] = v.z; dp[3] = v.w;
    }
    __syncthreads();

    int n_local = tid & 63;
    int co = __builtin_amdgcn_readfirstlane((tid >> 6) * 12);   // wave-uniform
    int node = nb + n_local;
    bool alive = node < N;
    const float* hrow = sh + n_local * HP;

    float acc[12];
#pragma unroll
    for (int j = 0; j < 12; ++j) acc[j] = b1[co + j];
#pragma unroll
    for (int k = 0; k < D; ++k) {
        float hk = hrow[k];
        const float4* wr = (const float4*)(w1 + k * D + co);
#pragma unroll
        for (int jc = 0; jc < 3; ++jc) {
            float4 wv = wr[jc];
            acc[4 * jc + 0] = fmaf(hk, wv.x, acc[4 * jc + 0]);
            acc[4 * jc + 1] = fmaf(hk, wv.y, acc[4 * jc + 1]);
            acc[4 * jc + 2] = fmaf(hk, wv.z, acc[4 * jc + 2]);
            acc[4 * jc + 3] = fmaf(hk, wv.w, acc[4 * jc + 3]);
        }
    }
#pragma unroll
    for (int j = 0; j < 12; ++j) acc[j] = fmaxf(acc[j], 0.0f);
    __syncthreads();                    // everyone done reading h tile
    {
        float* hw = sh + n_local * HP + co;
#pragma unroll
        for (int j = 0; j < 12; ++j) hw[j] = acc[j];
    }
    __syncthreads();                    // hid tile ready
#pragma unroll
    for (int j = 0; j < 12; ++j) acc[j] = b2[co + j];
#pragma unroll
    for (int k = 0; k < D; ++k) {
        float hk = hrow[k];
        const float4* wr = (const float4*)(w2 + k * D + co);
#pragma unroll
        for (int jc = 0; jc < 3; ++jc) {
            float4 wv = wr[jc];
            acc[4 * jc + 0] = fmaf(hk, wv.x, acc[4 * jc + 0]);
            acc[4 * jc + 1] = fmaf(hk, wv.y, acc[4 * jc + 1]);
            acc[4 * jc + 2] = fmaf(hk, wv.z, acc[4 * jc + 2]);
            acc[4 * jc + 3] = fmaf(hk, wv.w, acc[4 * jc + 3]);
        }
    }
    if (alive) {
        const float4* f4 = (const float4*)feat + (size_t)node * D4 + (co / 4);
        float4*       o4 = (float4*)rst + (size_t)node * D4 + (co / 4);
#pragma unroll
        for (int jc = 0; jc < 3; ++jc) {
            float4 fv = f4[jc];
            float4 o;
            o.x = acc[4 * jc + 0] + fv.x;
            o.y = acc[4 * jc + 1] + fv.y;
            o.z = acc[4 * jc + 2] + fv.z;
            o.w = acc[4 * jc + 3] + fv.w;
            o4[jc] = o;
        }
    }
}

extern "C" void kernel_launch(void* const* d_in, const int* in_sizes, int n_in,
                              void* d_out, int out_size, void* d_ws, size_t ws_size,
                              hipStream_t stream) {
    const float* feat = (const float*)d_in[0];
    const int*   src  = (const int*)d_in[1];
    const int*   dst  = (const int*)d_in[2];
    const float* w1   = (const float*)d_in[3];
    const float* b1   = (const float*)d_in[4];
    const float* w2   = (const float*)d_in[5];
    const float* b2   = (const float*)d_in[6];

    float* rst   = (float*)d_out;                  // output 0: [N, D]
    float* r_out = rst + (size_t)N * D;            // output 1: [N, D]

    // workspace layout (16B-aligned offsets)
    char*     w     = (char*)d_ws;
    int*      cnt4  = (int*)w;                               //  1,600,000 B
    float*    norm  = (float*)(w + 1600000);                 //    400,000 B
    ushort_t* ell16 = (ushort_t*)(w + 2000000);              // 19,200,000 B
    uint4*    sA    = (uint4*)(w + 2000000 + 19200000);      //  9,600,000 B
    uint4*    sB    = sA + (size_t)N * C8;                   //  9,600,000 B
    uint4*    h0s   = sB + (size_t)N * C8;                   //  9,600,000 B
    // build-phase scratch, dead before sA/sB are first written:
    uint*     bins  = (uint*)sA;                             //  8,388,608 B (aliases sA)
    int*      tails = (int*)sB;                              //     32,768 B (aliases sB)

    zero_kernel<<<(NPART * SUBS * TSTR + 255) / 256, 256, 0, stream>>>(tails);
    bin_scan_kernel<<<(E / 4 + 255) / 256, 256, 0, stream>>>(src, dst, bins, tails);
    build_window_kernel<<<NPART * NWIN, 256, 0, stream>>>(bins, tails, cnt4, ell16);
    norm_scaled0_kernel<<<(N * C8 + 255) / 256, 256, 0, stream>>>(
        cnt4, (const float4*)feat, norm, sA, h0s);

    uint4* bufs[2] = {sA, sB};
    for (int hop = 0; hop < 10; ++hop) {
        const uint4* in  = bufs[hop & 1];
        uint4*       out = bufs[(hop + 1) & 1];
        if (hop < 9) {
            agg_kernel<false><<<(HALF + 255) / 256, 256, 0, stream>>>(
                in, ell16, cnt4, norm, h0s, out, nullptr);
        } else {
            agg_kernel<true><<<(HALF + 255) / 256, 256, 0, stream>>>(
                in, ell16, cnt4, norm, h0s, nullptr, (float4*)r_out);
        }
    }

    ffn_kernel<<<(N + FNB - 1) / FNB, 256, 0, stream>>>(
        r_out, feat, w1, b1, w2, b2, rst);
}

// Round 4
// 529.808 us; speedup vs baseline: 1.4603x; 1.4603x over previous
//
#include <hip/hip_runtime.h>

// APPNP block: 10 hops of symmetric-normalized propagation + FFN + residual.
// Round 12: agg path unchanged (R6 fused lockstep, ~38us/hop).
// BUILD v4: R3's window build was right about layout (LDS ELL + coalesced
// writeback, WRITE 90->20MB) but wrong about work distribution: each block
// re-scanned its whole partition (50x redundant, 248us, VALUBusy 12.7%).
// Now Phase A is a 400-way LDS multisplit: stage 8192 packed edges in LDS,
// histogram (LDS atomics), reserve per-window space with one global atomic
// per (tile,window), scatter from LDS -> each window's bin is CONTIGUOUS.
// Phase B block w reads only its own ~4000-edge bin (coalesced), builds the
// 250-node ELL slice in LDS, writes back coalesced. 50x less scan work.
// FFN (R10): 4 thr/node, h tile in LDS stride 49, weights via wave-uniform
// scalar loads from global.

constexpr int N      = 100000;
constexpr int E      = 1600000;
constexpr int D      = 48;     // floats per node
constexpr int D4     = 12;     // float4 per node
constexpr int C8     = 6;      // chunks of 8 bf16 (16B) per node
constexpr int HALF   = N * C8 / 2;   // 300000 threads, 2 (n,c) pairs each
constexpr int NB     = 4;      // source buckets, width 25000
constexpr int BW     = 25000;  // bucket width (fits ushort local ids)
constexpr int BCAP   = 24;     // per-(node,bucket) cap; P(Bin(deg,1/4)>24) ~ 1e-8
constexpr int FNB    = 64;     // ffn nodes per block (256 thr = 64 nodes x 4 chunks)
constexpr int HP     = 49;     // padded LDS row stride (odd -> bank-conflict-free)
constexpr int WNODES = 250;    // nodes per window
constexpr int NWIN   = N / WNODES;   // 400 windows
constexpr int WCAP   = 5120;   // edges per window bin (mean 4000, sd 63 -> +17.8 sd)
constexpr int TILE   = 8192;   // edges per multisplit tile

typedef unsigned int uint;
typedef unsigned short ushort_t;
typedef uint  __attribute__((ext_vector_type(4))) nuint4;
typedef float __attribute__((ext_vector_type(4))) nfloat4;

__device__ __forceinline__ uint pack_bf16x2(float x, float y) {
    uint bx = __float_as_uint(x), by = __float_as_uint(y);
    bx = (bx + 0x7FFFu + ((bx >> 16) & 1u)) >> 16;          // RNE
    by = (by + 0x7FFFu + ((by >> 16) & 1u)) >> 16;
    return bx | (by << 16);
}

__device__ __forceinline__ void unpack_add(uint u, float& a0, float& a1) {
    a0 += __uint_as_float(u << 16);
    a1 += __uint_as_float(u & 0xFFFF0000u);
}

__global__ __launch_bounds__(256) void zero_kernel(int* __restrict__ tails) {
    int i = blockIdx.x * 256 + threadIdx.x;
    if (i < NWIN) tails[i] = 0;
}

// Phase A: 400-way LDS multisplit. Each block owns a tile of 8192 edges:
// stage packed (s<<9|dl) + window id in LDS, histogram windows (LDS atomics),
// reserve contiguous per-window space in the global bins (one atomicAdd per
// (tile,window)), then scatter from LDS. Each window's ~20 entries per tile
// are contiguous in its bin -> near-full-line writes; bins end up contiguous
// per window for Phase B.
__global__ __launch_bounds__(256) void bin_scan_kernel(const int* __restrict__ src,
                                                       const int* __restrict__ dst,
                                                       uint* __restrict__ bins,
                                                       int* __restrict__ tails) {
    __shared__ uint     se[TILE];       // packed edge: s<<9 | d_local   (32KB)
    __shared__ ushort_t sw[TILE];       // window id, 0xFFFF = invalid   (16KB)
    __shared__ int      hcnt[NWIN];     // histogram, then rank counter  (1.6KB)
    __shared__ int      hbase[NWIN];    // reserved global base          (1.6KB)

    int tid = threadIdx.x;
    int e0  = blockIdx.x * TILE;

    for (int w = tid; w < NWIN; w += 256) hcnt[w] = 0;
    __syncthreads();

    // stage + histogram
    for (int i = tid; i < TILE; i += 256) {
        int e = e0 + i;
        if (e < E) {
            int d = dst[e];
            int s = src[e];
            int wid = (uint)d / (uint)WNODES;       // magic mul
            int dl  = d - wid * WNODES;             // 0..249 (9 bits)
            se[i] = ((uint)s << 9) | (uint)dl;
            sw[i] = (ushort_t)wid;
            atomicAdd(&hcnt[wid], 1);
        } else {
            sw[i] = 0xFFFFu;
        }
    }
    __syncthreads();

    // reserve global space per window present in this tile
    for (int w = tid; w < NWIN; w += 256) {
        int c = hcnt[w];
        hbase[w] = c ? atomicAdd(&tails[w], c) : 0;
        hcnt[w] = 0;                                // reuse as rank counter
    }
    __syncthreads();

    // scatter: window's entries go to consecutive slots of its bin
    for (int i = tid; i < TILE; i += 256) {
        uint wid = sw[i];
        if (wid == 0xFFFFu) continue;
        int rank = atomicAdd(&hcnt[wid], 1);
        int pos  = hbase[wid] + rank;
        if (pos < WCAP) bins[(size_t)wid * WCAP + pos] = se[i];
    }
}

// Phase B: block w reads ONLY its window's contiguous bin (~4000 edges,
// 16KB coalesced), accumulates the 250-node ELL slice + counts in LDS
// (LDS atomics), then writes the slice back with coalesced uint4 stores.
// True in-degree preserved: lcnt counts every edge, cap only limits stores.
__global__ __launch_bounds__(256) void build_window_kernel(const uint* __restrict__ bins,
                                                           const int* __restrict__ tails,
                                                           int* __restrict__ cnt4,
                                                           ushort_t* __restrict__ ell16) {
    __shared__ int lcnt[WNODES * NB];                       //  4000 B
    __shared__ __align__(16) ushort_t lell[WNODES * NB * BCAP];  // 48000 B

    int w   = blockIdx.x;
    int tid = threadIdx.x;

    for (int i = tid; i < WNODES * NB; i += 256) lcnt[i] = 0;
    __syncthreads();

    int cnt = tails[w];
    if (cnt > WCAP) cnt = WCAP;
    const uint* bs = bins + (size_t)w * WCAP;
    for (int i = tid; i < cnt; i += 256) {
        uint u = bs[i];
        int dl = (int)(u & 0x1FFu);
        int s  = (int)(u >> 9);
        int b = (s >= BW) + (s >= 2 * BW) + (s >= 3 * BW);
        int lidx = dl * NB + b;
        int cpos = atomicAdd(&lcnt[lidx], 1);
        if (cpos < BCAP) lell[lidx * BCAP + cpos] = (ushort_t)(s - b * BW);
    }
    __syncthreads();

    int nbase = w * WNODES;
    int* gcnt = cnt4 + (size_t)nbase * NB;
    for (int i = tid; i < WNODES * NB; i += 256) gcnt[i] = lcnt[i];
    const uint4* l4 = (const uint4*)lell;
    uint4* g4 = (uint4*)(ell16 + (size_t)nbase * NB * BCAP);
    constexpr int NV4 = WNODES * NB * BCAP * 2 / 16;        // 3000
    for (int i = tid; i < NV4; i += 256)
        __builtin_nontemporal_store(*(const nuint4*)&l4[i], (nuint4*)&g4[i]);
}

// scaled0 = feat*norm (bf16, node-major 96B rows) and h0s = 0.1*feat (bf16).
// True in-degree = raw sum of the 4 bucket counters (cap only limits gathers).
__global__ __launch_bounds__(256) void norm_scaled0_kernel(const int* __restrict__ cnt4,
                                                           const float4* __restrict__ feat,
                                                           float* __restrict__ norm,
                                                           uint4* __restrict__ sA,
                                                           uint4* __restrict__ h0s) {
    int t = blockIdx.x * 256 + threadIdx.x;
    if (t >= N * C8) return;
    int n = t / C8;
    int c = t - n * C8;
    int4 cc = *(const int4*)(cnt4 + n * NB);
    float dg = (float)(cc.x + cc.y + cc.z + cc.w);
    float nm = 1.0f / sqrtf(fmaxf(dg, 1.0f));
    if (c == 0) norm[n] = nm;
    float4 v0 = feat[n * D4 + c * 2];
    float4 v1 = feat[n * D4 + c * 2 + 1];
    uint4 o;
    o.x = pack_bf16x2(v0.x * nm, v0.y * nm);
    o.y = pack_bf16x2(v0.z * nm, v0.w * nm);
    o.z = pack_bf16x2(v1.x * nm, v1.y * nm);
    o.w = pack_bf16x2(v1.z * nm, v1.w * nm);
    sA[t] = o;
    uint4 h;
    h.x = pack_bf16x2(v0.x * 0.1f, v0.y * 0.1f);
    h.y = pack_bf16x2(v0.z * 0.1f, v0.w * 0.1f);
    h.z = pack_bf16x2(v1.x * 0.1f, v1.y * 0.1f);
    h.w = pack_bf16x2(v1.z * 0.1f, v1.w * 0.1f);
    h0s[t] = h;
}

// Fused lockstep agg (R6): thread i owns (n0=i/6, c) and (n1=n0+50000, c).
// Bucket loop outermost; grid 1172 blocks = 4688 waves, fully co-resident.
// 6 consecutive lanes read one source node's contiguous 96B bf16 row.
template <bool LAST>
__global__ __launch_bounds__(256) void agg_kernel(const uint4* __restrict__ scaled_in,
                                                  const ushort_t* __restrict__ ell16,
                                                  const int* __restrict__ cnt4,
                                                  const float* __restrict__ norm,
                                                  const uint4* __restrict__ h0s,
                                                  uint4* __restrict__ scaled_out,
                                                  float4* __restrict__ h_out) {
    int i = blockIdx.x * 256 + threadIdx.x;
    if (i >= HALF) return;
    int n0 = i / C8;
    int c  = i - n0 * C8;
    int n1 = n0 + N / 2;
    int t0 = i, t1 = i + HALF;

    int4 cc0 = *(const int4*)(cnt4 + n0 * NB);
    int4 cc1 = *(const int4*)(cnt4 + n1 * NB);
    int cb0[NB] = {min(cc0.x, BCAP), min(cc0.y, BCAP), min(cc0.z, BCAP), min(cc0.w, BCAP)};
    int cb1[NB] = {min(cc1.x, BCAP), min(cc1.y, BCAP), min(cc1.z, BCAP), min(cc1.w, BCAP)};
    float nm0 = norm[n0], nm1 = norm[n1];
    const ushort_t* r0 = ell16 + (size_t)n0 * (NB * BCAP);
    const ushort_t* r1 = ell16 + (size_t)n1 * (NB * BCAP);

    float a0[8] = {0.f, 0.f, 0.f, 0.f, 0.f, 0.f, 0.f, 0.f};
    float a1[8] = {0.f, 0.f, 0.f, 0.f, 0.f, 0.f, 0.f, 0.f};

    auto addv = [](uint4 v, float* a) {
        unpack_add(v.x, a[0], a[1]); unpack_add(v.y, a[2], a[3]);
        unpack_add(v.z, a[4], a[5]); unpack_add(v.w, a[6], a[7]);
    };
    auto run = [&](const ushort_t* row, int cnt, const uint4* base, float* a) {
        int j = 0;
        for (; j + 4 <= cnt; j += 4) {
            int s0 = row[j], s1 = row[j + 1], s2 = row[j + 2], s3 = row[j + 3];
            uint4 v0 = base[s0 * C8];
            uint4 v1 = base[s1 * C8];
            uint4 v2 = base[s2 * C8];
            uint4 v3 = base[s3 * C8];
            addv(v0, a); addv(v1, a); addv(v2, a); addv(v3, a);
        }
        for (; j < cnt; ++j) {
            uint4 v = base[row[j] * C8];
            addv(v, a);
        }
    };

#pragma unroll
    for (int p = 0; p < NB; ++p) {
        const uint4* base = scaled_in + (size_t)p * (BW * C8) + c;
        run(r0 + p * BCAP, cb0[p], base, a0);
        run(r1 + p * BCAP, cb1[p], base, a1);
    }

    auto finish = [&](int t, int n, float nm, float* a) {
        nuint4 hs = __builtin_nontemporal_load((const nuint4*)&h0s[t]);
        float rr[8] = {0.f, 0.f, 0.f, 0.f, 0.f, 0.f, 0.f, 0.f};
        unpack_add(hs.x, rr[0], rr[1]); unpack_add(hs.y, rr[2], rr[3]);
        unpack_add(hs.z, rr[4], rr[5]); unpack_add(hs.w, rr[6], rr[7]);
        float s = 0.9f * nm;
        float hv[8];
#pragma unroll
        for (int k = 0; k < 8; ++k) hv[k] = fmaf(s, a[k], rr[k]);
        if (LAST) {
            nfloat4 o0 = {hv[0], hv[1], hv[2], hv[3]};
            nfloat4 o1 = {hv[4], hv[5], hv[6], hv[7]};
            __builtin_nontemporal_store(o0, (nfloat4*)&h_out[n * D4 + c * 2]);
            __builtin_nontemporal_store(o1, (nfloat4*)&h_out[n * D4 + c * 2 + 1]);
        } else {
            nuint4 o;
            o.x = pack_bf16x2(hv[0] * nm, hv[1] * nm);
            o.y = pack_bf16x2(hv[2] * nm, hv[3] * nm);
            o.z = pack_bf16x2(hv[4] * nm, hv[5] * nm);
            o.w = pack_bf16x2(hv[6] * nm, hv[7] * nm);
            __builtin_nontemporal_store(o, (nuint4*)&scaled_out[t]);
        }
    };
    finish(t0, n0, nm0, a0);
    finish(t1, n1, nm1, a1);
}

// rst = relu(h@w1 + b1)@w2 + b2 + features.
// 4 threads per node (chunk = tid>>6 owns 12 outputs), 64 nodes per block.
// h row staged in LDS stride 49 (free 2-way bank alias on scalar reads);
// hid reuses the same buffer between barriers. Weights/biases are read with
// wave-uniform SCALAR loads from global (co = readfirstlane, uniform control
// flow; only the final store is guarded) -> no DS-pipe cost for weights.
__global__ __launch_bounds__(256) void ffn_kernel(const float* __restrict__ r,
                                                  const float* __restrict__ feat,
                                                  const float* __restrict__ w1,
                                                  const float* __restrict__ b1,
                                                  const float* __restrict__ w2,
                                                  const float* __restrict__ b2,
                                                  float* __restrict__ rst) {
    __shared__ float sh[FNB * HP];      // h tile, reused for hid

    int tid = threadIdx.x;
    int nb = blockIdx.x * FNB;
    // stage h rows: up to 64 rows x 12 float4, coalesced global reads
    const float4* r4 = (const float4*)r + (size_t)nb * D4;
    int maxf4 = (N - nb) * D4;
    if (maxf4 > FNB * D4) maxf4 = FNB * D4;
    for (int f = tid; f < maxf4; f += 256) {
        float4 v = r4[f];
        int row = f / D4;
        int col = (f - row * D4) * 4;
        float* dp = sh + row * HP + col;
        dp[0] = v.x; dp[1] = v.y; dp[2] = v.z; dp[3] = v.w;
    }
    __syncthreads();

    int n_local = tid & 63;
    int co = __builtin_amdgcn_readfirstlane((tid >> 6) * 12);   // wave-uniform
    int node = nb + n_local;
    bool alive = node < N;
    const float* hrow = sh + n_local * HP;

    float acc[12];
#pragma unroll
    for (int j = 0; j < 12; ++j) acc[j] = b1[co + j];
#pragma unroll
    for (int k = 0; k < D; ++k) {
        float hk = hrow[k];
        const float4* wr = (const float4*)(w1 + k * D + co);
#pragma unroll
        for (int jc = 0; jc < 3; ++jc) {
            float4 wv = wr[jc];
            acc[4 * jc + 0] = fmaf(hk, wv.x, acc[4 * jc + 0]);
            acc[4 * jc + 1] = fmaf(hk, wv.y, acc[4 * jc + 1]);
            acc[4 * jc + 2] = fmaf(hk, wv.z, acc[4 * jc + 2]);
            acc[4 * jc + 3] = fmaf(hk, wv.w, acc[4 * jc + 3]);
        }
    }
#pragma unroll
    for (int j = 0; j < 12; ++j) acc[j] = fmaxf(acc[j], 0.0f);
    __syncthreads();                    // everyone done reading h tile
    {
        float* hw = sh + n_local * HP + co;
#pragma unroll
        for (int j = 0; j < 12; ++j) hw[j] = acc[j];
    }
    __syncthreads();                    // hid tile ready
#pragma unroll
    for (int j = 0; j < 12; ++j) acc[j] = b2[co + j];
#pragma unroll
    for (int k = 0; k < D; ++k) {
        float hk = hrow[k];
        const float4* wr = (const float4*)(w2 + k * D + co);
#pragma unroll
        for (int jc = 0; jc < 3; ++jc) {
            float4 wv = wr[jc];
            acc[4 * jc + 0] = fmaf(hk, wv.x, acc[4 * jc + 0]);
            acc[4 * jc + 1] = fmaf(hk, wv.y, acc[4 * jc + 1]);
            acc[4 * jc + 2] = fmaf(hk, wv.z, acc[4 * jc + 2]);
            acc[4 * jc + 3] = fmaf(hk, wv.w, acc[4 * jc + 3]);
        }
    }
    if (alive) {
        const float4* f4 = (const float4*)feat + (size_t)node * D4 + (co / 4);
        float4*       o4 = (float4*)rst + (size_t)node * D4 + (co / 4);
#pragma unroll
        for (int jc = 0; jc < 3; ++jc) {
            float4 fv = f4[jc];
            float4 o;
            o.x = acc[4 * jc + 0] + fv.x;
            o.y = acc[4 * jc + 1] + fv.y;
            o.z = acc[4 * jc + 2] + fv.z;
            o.w = acc[4 * jc + 3] + fv.w;
            o4[jc] = o;
        }
    }
}

extern "C" void kernel_launch(void* const* d_in, const int* in_sizes, int n_in,
                              void* d_out, int out_size, void* d_ws, size_t ws_size,
                              hipStream_t stream) {
    const float* feat = (const float*)d_in[0];
    const int*   src  = (const int*)d_in[1];
    const int*   dst  = (const int*)d_in[2];
    const float* w1   = (const float*)d_in[3];
    const float* b1   = (const float*)d_in[4];
    const float* w2   = (const float*)d_in[5];
    const float* b2   = (const float*)d_in[6];

    float* rst   = (float*)d_out;                  // output 0: [N, D]
    float* r_out = rst + (size_t)N * D;            // output 1: [N, D]

    // workspace layout (16B-aligned offsets)
    char*     w     = (char*)d_ws;
    int*      cnt4  = (int*)w;                               //  1,600,000 B
    float*    norm  = (float*)(w + 1600000);                 //    400,000 B
    ushort_t* ell16 = (ushort_t*)(w + 2000000);              // 19,200,000 B
    uint4*    sA    = (uint4*)(w + 2000000 + 19200000);      //  9,600,000 B
    uint4*    sB    = sA + (size_t)N * C8;                   //  9,600,000 B
    uint4*    h0s   = sB + (size_t)N * C8;                   //  9,600,000 B
    // build-phase scratch, dead before sA/sB are first written:
    uint*     bins  = (uint*)sA;                             //  8,192,000 B (aliases sA)
    int*      tails = (int*)sB;                              //      1,600 B (aliases sB)

    zero_kernel<<<(NWIN + 255) / 256, 256, 0, stream>>>(tails);
    bin_scan_kernel<<<(E + TILE - 1) / TILE, 256, 0, stream>>>(src, dst, bins, tails);
    build_window_kernel<<<NWIN, 256, 0, stream>>>(bins, tails, cnt4, ell16);
    norm_scaled0_kernel<<<(N * C8 + 255) / 256, 256, 0, stream>>>(
        cnt4, (const float4*)feat, norm, sA, h0s);

    uint4* bufs[2] = {sA, sB};
    for (int hop = 0; hop < 10; ++hop) {
        const uint4* in  = bufs[hop & 1];
        uint4*       out = bufs[(hop + 1) & 1];
        if (hop < 9) {
            agg_kernel<false><<<(HALF + 255) / 256, 256, 0, stream>>>(
                in, ell16, cnt4, norm, h0s, out, nullptr);
        } else {
            agg_kernel<true><<<(HALF + 255) / 256, 256, 0, stream>>>(
                in, ell16, cnt4, norm, h0s, nullptr, (float4*)r_out);
        }
    }

    ffn_kernel<<<(N + FNB - 1) / FNB, 256, 0, stream>>>(
        r_out, feat, w1, b1, w2, b2, rst);
}

// Round 5
// 524.570 us; speedup vs baseline: 1.4749x; 1.0100x over previous
//
#include <hip/hip_runtime.h>

// APPNP block: 10 hops of symmetric-normalized propagation + FFN + residual.
// Round 13: agg path unchanged (R6 fused lockstep, ~38us/hop). Build v4
// (multisplit + window build) unchanged, out of top-5.
// FFN v3: R1's "scalar weight loads" thrashed the ~16KB scalar K$ (288
// s_load_dwordx4/wave over 18.4KB x2 of weights -> serial L2-latency stalls,
// VALUBusy 18%, 46us). Weights go BACK to LDS (the R0 100us failure was
// scratch spill from thread-per-node, not LDS weights: 288 wave-uniform
// broadcast ds_read_b128/wave x 24 waves/CU = ~1.4us on the 256B/clk DS
// pipe). Keep the 4-thr/node x 12-output structure (VGPR 32, no spill).
// LDS 31.4KB -> 5 blocks/CU.

constexpr int N      = 100000;
constexpr int E      = 1600000;
constexpr int D      = 48;     // floats per node
constexpr int D4     = 12;     // float4 per node
constexpr int C8     = 6;      // chunks of 8 bf16 (16B) per node
constexpr int HALF   = N * C8 / 2;   // 300000 threads, 2 (n,c) pairs each
constexpr int NB     = 4;      // source buckets, width 25000
constexpr int BW     = 25000;  // bucket width (fits ushort local ids)
constexpr int BCAP   = 24;     // per-(node,bucket) cap; P(Bin(deg,1/4)>24) ~ 1e-8
constexpr int FNB    = 64;     // ffn nodes per block (256 thr = 64 nodes x 4 chunks)
constexpr int HP     = 49;     // padded LDS row stride (odd -> bank-conflict-free)
constexpr int WNODES = 250;    // nodes per window
constexpr int NWIN   = N / WNODES;   // 400 windows
constexpr int WCAP   = 5120;   // edges per window bin (mean 4000, sd 63 -> +17.8 sd)
constexpr int TILE   = 8192;   // edges per multisplit tile

typedef unsigned int uint;
typedef unsigned short ushort_t;
typedef uint  __attribute__((ext_vector_type(4))) nuint4;
typedef float __attribute__((ext_vector_type(4))) nfloat4;

__device__ __forceinline__ uint pack_bf16x2(float x, float y) {
    uint bx = __float_as_uint(x), by = __float_as_uint(y);
    bx = (bx + 0x7FFFu + ((bx >> 16) & 1u)) >> 16;          // RNE
    by = (by + 0x7FFFu + ((by >> 16) & 1u)) >> 16;
    return bx | (by << 16);
}

__device__ __forceinline__ void unpack_add(uint u, float& a0, float& a1) {
    a0 += __uint_as_float(u << 16);
    a1 += __uint_as_float(u & 0xFFFF0000u);
}

__global__ __launch_bounds__(256) void zero_kernel(int* __restrict__ tails) {
    int i = blockIdx.x * 256 + threadIdx.x;
    if (i < NWIN) tails[i] = 0;
}

// Phase A: 400-way LDS multisplit. Each block owns a tile of 8192 edges:
// stage packed (s<<9|dl) + window id in LDS, histogram windows (LDS atomics),
// reserve contiguous per-window space in the global bins (one atomicAdd per
// (tile,window)), then scatter from LDS. Each window's ~20 entries per tile
// are contiguous in its bin -> near-full-line writes; bins end up contiguous
// per window for Phase B.
__global__ __launch_bounds__(256) void bin_scan_kernel(const int* __restrict__ src,
                                                       const int* __restrict__ dst,
                                                       uint* __restrict__ bins,
                                                       int* __restrict__ tails) {
    __shared__ uint     se[TILE];       // packed edge: s<<9 | d_local   (32KB)
    __shared__ ushort_t sw[TILE];       // window id, 0xFFFF = invalid   (16KB)
    __shared__ int      hcnt[NWIN];     // histogram, then rank counter  (1.6KB)
    __shared__ int      hbase[NWIN];    // reserved global base          (1.6KB)

    int tid = threadIdx.x;
    int e0  = blockIdx.x * TILE;

    for (int w = tid; w < NWIN; w += 256) hcnt[w] = 0;
    __syncthreads();

    // stage + histogram
    for (int i = tid; i < TILE; i += 256) {
        int e = e0 + i;
        if (e < E) {
            int d = dst[e];
            int s = src[e];
            int wid = (uint)d / (uint)WNODES;       // magic mul
            int dl  = d - wid * WNODES;             // 0..249 (9 bits)
            se[i] = ((uint)s << 9) | (uint)dl;
            sw[i] = (ushort_t)wid;
            atomicAdd(&hcnt[wid], 1);
        } else {
            sw[i] = 0xFFFFu;
        }
    }
    __syncthreads();

    // reserve global space per window present in this tile
    for (int w = tid; w < NWIN; w += 256) {
        int c = hcnt[w];
        hbase[w] = c ? atomicAdd(&tails[w], c) : 0;
        hcnt[w] = 0;                                // reuse as rank counter
    }
    __syncthreads();

    // scatter: window's entries go to consecutive slots of its bin
    for (int i = tid; i < TILE; i += 256) {
        uint wid = sw[i];
        if (wid == 0xFFFFu) continue;
        int rank = atomicAdd(&hcnt[wid], 1);
        int pos  = hbase[wid] + rank;
        if (pos < WCAP) bins[(size_t)wid * WCAP + pos] = se[i];
    }
}

// Phase B: block w reads ONLY its window's contiguous bin (~4000 edges,
// 16KB coalesced), accumulates the 250-node ELL slice + counts in LDS
// (LDS atomics), then writes the slice back with coalesced uint4 stores.
// True in-degree preserved: lcnt counts every edge, cap only limits stores.
__global__ __launch_bounds__(256) void build_window_kernel(const uint* __restrict__ bins,
                                                           const int* __restrict__ tails,
                                                           int* __restrict__ cnt4,
                                                           ushort_t* __restrict__ ell16) {
    __shared__ int lcnt[WNODES * NB];                       //  4000 B
    __shared__ __align__(16) ushort_t lell[WNODES * NB * BCAP];  // 48000 B

    int w   = blockIdx.x;
    int tid = threadIdx.x;

    for (int i = tid; i < WNODES * NB; i += 256) lcnt[i] = 0;
    __syncthreads();

    int cnt = tails[w];
    if (cnt > WCAP) cnt = WCAP;
    const uint* bs = bins + (size_t)w * WCAP;
    for (int i = tid; i < cnt; i += 256) {
        uint u = bs[i];
        int dl = (int)(u & 0x1FFu);
        int s  = (int)(u >> 9);
        int b = (s >= BW) + (s >= 2 * BW) + (s >= 3 * BW);
        int lidx = dl * NB + b;
        int cpos = atomicAdd(&lcnt[lidx], 1);
        if (cpos < BCAP) lell[lidx * BCAP + cpos] = (ushort_t)(s - b * BW);
    }
    __syncthreads();

    int nbase = w * WNODES;
    int* gcnt = cnt4 + (size_t)nbase * NB;
    for (int i = tid; i < WNODES * NB; i += 256) gcnt[i] = lcnt[i];
    const uint4* l4 = (const uint4*)lell;
    uint4* g4 = (uint4*)(ell16 + (size_t)nbase * NB * BCAP);
    constexpr int NV4 = WNODES * NB * BCAP * 2 / 16;        // 3000
    for (int i = tid; i < NV4; i += 256)
        __builtin_nontemporal_store(*(const nuint4*)&l4[i], (nuint4*)&g4[i]);
}

// scaled0 = feat*norm (bf16, node-major 96B rows) and h0s = 0.1*feat (bf16).
// True in-degree = raw sum of the 4 bucket counters (cap only limits gathers).
__global__ __launch_bounds__(256) void norm_scaled0_kernel(const int* __restrict__ cnt4,
                                                           const float4* __restrict__ feat,
                                                           float* __restrict__ norm,
                                                           uint4* __restrict__ sA,
                                                           uint4* __restrict__ h0s) {
    int t = blockIdx.x * 256 + threadIdx.x;
    if (t >= N * C8) return;
    int n = t / C8;
    int c = t - n * C8;
    int4 cc = *(const int4*)(cnt4 + n * NB);
    float dg = (float)(cc.x + cc.y + cc.z + cc.w);
    float nm = 1.0f / sqrtf(fmaxf(dg, 1.0f));
    if (c == 0) norm[n] = nm;
    float4 v0 = feat[n * D4 + c * 2];
    float4 v1 = feat[n * D4 + c * 2 + 1];
    uint4 o;
    o.x = pack_bf16x2(v0.x * nm, v0.y * nm);
    o.y = pack_bf16x2(v0.z * nm, v0.w * nm);
    o.z = pack_bf16x2(v1.x * nm, v1.y * nm);
    o.w = pack_bf16x2(v1.z * nm, v1.w * nm);
    sA[t] = o;
    uint4 h;
    h.x = pack_bf16x2(v0.x * 0.1f, v0.y * 0.1f);
    h.y = pack_bf16x2(v0.z * 0.1f, v0.w * 0.1f);
    h.z = pack_bf16x2(v1.x * 0.1f, v1.y * 0.1f);
    h.w = pack_bf16x2(v1.z * 0.1f, v1.w * 0.1f);
    h0s[t] = h;
}

// Fused lockstep agg (R6): thread i owns (n0=i/6, c) and (n1=n0+50000, c).
// Bucket loop outermost; grid 1172 blocks = 4688 waves, fully co-resident.
// 6 consecutive lanes read one source node's contiguous 96B bf16 row.
template <bool LAST>
__global__ __launch_bounds__(256) void agg_kernel(const uint4* __restrict__ scaled_in,
                                                  const ushort_t* __restrict__ ell16,
                                                  const int* __restrict__ cnt4,
                                                  const float* __restrict__ norm,
                                                  const uint4* __restrict__ h0s,
                                                  uint4* __restrict__ scaled_out,
                                                  float4* __restrict__ h_out) {
    int i = blockIdx.x * 256 + threadIdx.x;
    if (i >= HALF) return;
    int n0 = i / C8;
    int c  = i - n0 * C8;
    int n1 = n0 + N / 2;
    int t0 = i, t1 = i + HALF;

    int4 cc0 = *(const int4*)(cnt4 + n0 * NB);
    int4 cc1 = *(const int4*)(cnt4 + n1 * NB);
    int cb0[NB] = {min(cc0.x, BCAP), min(cc0.y, BCAP), min(cc0.z, BCAP), min(cc0.w, BCAP)};
    int cb1[NB] = {min(cc1.x, BCAP), min(cc1.y, BCAP), min(cc1.z, BCAP), min(cc1.w, BCAP)};
    float nm0 = norm[n0], nm1 = norm[n1];
    const ushort_t* r0 = ell16 + (size_t)n0 * (NB * BCAP);
    const ushort_t* r1 = ell16 + (size_t)n1 * (NB * BCAP);

    float a0[8] = {0.f, 0.f, 0.f, 0.f, 0.f, 0.f, 0.f, 0.f};
    float a1[8] = {0.f, 0.f, 0.f, 0.f, 0.f, 0.f, 0.f, 0.f};

    auto addv = [](uint4 v, float* a) {
        unpack_add(v.x, a[0], a[1]); unpack_add(v.y, a[2], a[3]);
        unpack_add(v.z, a[4], a[5]); unpack_add(v.w, a[6], a[7]);
    };
    auto run = [&](const ushort_t* row, int cnt, const uint4* base, float* a) {
        int j = 0;
        for (; j + 4 <= cnt; j += 4) {
            int s0 = row[j], s1 = row[j + 1], s2 = row[j + 2], s3 = row[j + 3];
            uint4 v0 = base[s0 * C8];
            uint4 v1 = base[s1 * C8];
            uint4 v2 = base[s2 * C8];
            uint4 v3 = base[s3 * C8];
            addv(v0, a); addv(v1, a); addv(v2, a); addv(v3, a);
        }
        for (; j < cnt; ++j) {
            uint4 v = base[row[j] * C8];
            addv(v, a);
        }
    };

#pragma unroll
    for (int p = 0; p < NB; ++p) {
        const uint4* base = scaled_in + (size_t)p * (BW * C8) + c;
        run(r0 + p * BCAP, cb0[p], base, a0);
        run(r1 + p * BCAP, cb1[p], base, a1);
    }

    auto finish = [&](int t, int n, float nm, float* a) {
        nuint4 hs = __builtin_nontemporal_load((const nuint4*)&h0s[t]);
        float rr[8] = {0.f, 0.f, 0.f, 0.f, 0.f, 0.f, 0.f, 0.f};
        unpack_add(hs.x, rr[0], rr[1]); unpack_add(hs.y, rr[2], rr[3]);
        unpack_add(hs.z, rr[4], rr[5]); unpack_add(hs.w, rr[6], rr[7]);
        float s = 0.9f * nm;
        float hv[8];
#pragma unroll
        for (int k = 0; k < 8; ++k) hv[k] = fmaf(s, a[k], rr[k]);
        if (LAST) {
            nfloat4 o0 = {hv[0], hv[1], hv[2], hv[3]};
            nfloat4 o1 = {hv[4], hv[5], hv[6], hv[7]};
            __builtin_nontemporal_store(o0, (nfloat4*)&h_out[n * D4 + c * 2]);
            __builtin_nontemporal_store(o1, (nfloat4*)&h_out[n * D4 + c * 2 + 1]);
        } else {
            nuint4 o;
            o.x = pack_bf16x2(hv[0] * nm, hv[1] * nm);
            o.y = pack_bf16x2(hv[2] * nm, hv[3] * nm);
            o.z = pack_bf16x2(hv[4] * nm, hv[5] * nm);
            o.w = pack_bf16x2(hv[6] * nm, hv[7] * nm);
            __builtin_nontemporal_store(o, (nuint4*)&scaled_out[t]);
        }
    };
    finish(t0, n0, nm0, a0);
    finish(t1, n1, nm1, a1);
}

// rst = relu(h@w1 + b1)@w2 + b2 + features.
// 4 threads per node (chunk = tid>>6 owns 12 outputs), 64 nodes per block.
// h row staged in LDS stride 49 (free 2-way bank alias on scalar reads);
// hid reuses the same buffer between barriers. Weights + biases in LDS:
// wave-uniform addresses -> broadcast ds_read_b128, conflict-free; DS-pipe
// cost ~1.4us aggregate at 256B/clk (vs scalar-K$ thrash at 46us in R1).
__global__ __launch_bounds__(256) void ffn_kernel(const float* __restrict__ r,
                                                  const float* __restrict__ feat,
                                                  const float* __restrict__ w1,
                                                  const float* __restrict__ b1,
                                                  const float* __restrict__ w2,
                                                  const float* __restrict__ b2,
                                                  float* __restrict__ rst) {
    __shared__ __align__(16) float sw1[D * D];   // 9216 B
    __shared__ __align__(16) float sw2[D * D];   // 9216 B
    __shared__ float sb[2 * D];                  //  384 B
    __shared__ float sh[FNB * HP];               // 12544 B  (h tile, reused for hid)

    int tid = threadIdx.x;
    for (int i = tid; i < D * D; i += 256) {
        sw1[i] = w1[i];
        sw2[i] = w2[i];
    }
    if (tid < D) {
        sb[tid] = b1[tid];
        sb[D + tid] = b2[tid];
    }

    int nb = blockIdx.x * FNB;
    // stage h rows: up to 64 rows x 12 float4, coalesced global reads
    const float4* r4 = (const float4*)r + (size_t)nb * D4;
    int maxf4 = (N - nb) * D4;
    if (maxf4 > FNB * D4) maxf4 = FNB * D4;
    for (int f = tid; f < maxf4; f += 256) {
        float4 v = r4[f];
        int row = f / D4;
        int col = (f - row * D4) * 4;
        float* dp = sh + row * HP + col;
        dp[0] = v.x; dp[1] = v.y; dp[2] = v.z; dp[3] = v.w;
    }
    __syncthreads();

    int n_local = tid & 63;
    int co = __builtin_amdgcn_readfirstlane((tid >> 6) * 12);   // wave-uniform
    int node = nb + n_local;
    bool alive = node < N;
    const float* hrow = sh + n_local * HP;

    float acc[12];
#pragma unroll
    for (int j = 0; j < 12; ++j) acc[j] = sb[co + j];
#pragma unroll
    for (int k = 0; k < D; ++k) {
        float hk = hrow[k];
        const float4* wr = (const float4*)(sw1 + k * D + co);
#pragma unroll
        for (int jc = 0; jc < 3; ++jc) {
            float4 wv = wr[jc];
            acc[4 * jc + 0] = fmaf(hk, wv.x, acc[4 * jc + 0]);
            acc[4 * jc + 1] = fmaf(hk, wv.y, acc[4 * jc + 1]);
            acc[4 * jc + 2] = fmaf(hk, wv.z, acc[4 * jc + 2]);
            acc[4 * jc + 3] = fmaf(hk, wv.w, acc[4 * jc + 3]);
        }
    }
#pragma unroll
    for (int j = 0; j < 12; ++j) acc[j] = fmaxf(acc[j], 0.0f);
    __syncthreads();                    // everyone done reading h tile
    {
        float* hw = sh + n_local * HP + co;
#pragma unroll
        for (int j = 0; j < 12; ++j) hw[j] = acc[j];
    }
    __syncthreads();                    // hid tile ready
#pragma unroll
    for (int j = 0; j < 12; ++j) acc[j] = sb[D + co + j];
#pragma unroll
    for (int k = 0; k < D; ++k) {
        float hk = hrow[k];
        const float4* wr = (const float4*)(sw2 + k * D + co);
#pragma unroll
        for (int jc = 0; jc < 3; ++jc) {
            float4 wv = wr[jc];
            acc[4 * jc + 0] = fmaf(hk, wv.x, acc[4 * jc + 0]);
            acc[4 * jc + 1] = fmaf(hk, wv.y, acc[4 * jc + 1]);
            acc[4 * jc + 2] = fmaf(hk, wv.z, acc[4 * jc + 2]);
            acc[4 * jc + 3] = fmaf(hk, wv.w, acc[4 * jc + 3]);
        }
    }
    if (alive) {
        const float4* f4 = (const float4*)feat + (size_t)node * D4 + (co / 4);
        float4*       o4 = (float4*)rst + (size_t)node * D4 + (co / 4);
#pragma unroll
        for (int jc = 0; jc < 3; ++jc) {
            float4 fv = f4[jc];
            float4 o;
            o.x = acc[4 * jc + 0] + fv.x;
            o.y = acc[4 * jc + 1] + fv.y;
            o.z = acc[4 * jc + 2] + fv.z;
            o.w = acc[4 * jc + 3] + fv.w;
            o4[jc] = o;
        }
    }
}

extern "C" void kernel_launch(void* const* d_in, const int* in_sizes, int n_in,
                              void* d_out, int out_size, void* d_ws, size_t ws_size,
                              hipStream_t stream) {
    const float* feat = (const float*)d_in[0];
    const int*   src  = (const int*)d_in[1];
    const int*   dst  = (const int*)d_in[2];
    const float* w1   = (const float*)d_in[3];
    const float* b1   = (const float*)d_in[4];
    const float* w2   = (const float*)d_in[5];
    const float* b2   = (const float*)d_in[6];

    float* rst   = (float*)d_out;                  // output 0: [N, D]
    float* r_out = rst + (size_t)N * D;            // output 1: [N, D]

    // workspace layout (16B-aligned offsets)
    char*     w     = (char*)d_ws;
    int*      cnt4  = (int*)w;                               //  1,600,000 B
    float*    norm  = (float*)(w + 1600000);                 //    400,000 B
    ushort_t* ell16 = (ushort_t*)(w + 2000000);              // 19,200,000 B
    uint4*    sA    = (uint4*)(w + 2000000 + 19200000);      //  9,600,000 B
    uint4*    sB    = sA + (size_t)N * C8;                   //  9,600,000 B
    uint4*    h0s   = sB + (size_t)N * C8;                   //  9,600,000 B
    // build-phase scratch, dead before sA/sB are first written:
    uint*     bins  = (uint*)sA;                             //  8,192,000 B (aliases sA)
    int*      tails = (int*)sB;                              //      1,600 B (aliases sB)

    zero_kernel<<<(NWIN + 255) / 256, 256, 0, stream>>>(tails);
    bin_scan_kernel<<<(E + TILE - 1) / TILE, 256, 0, stream>>>(src, dst, bins, tails);
    build_window_kernel<<<NWIN, 256, 0, stream>>>(bins, tails, cnt4, ell16);
    norm_scaled0_kernel<<<(N * C8 + 255) / 256, 256, 0, stream>>>(
        cnt4, (const float4*)feat, norm, sA, h0s);

    uint4* bufs[2] = {sA, sB};
    for (int hop = 0; hop < 10; ++hop) {
        const uint4* in  = bufs[hop & 1];
        uint4*       out = bufs[(hop + 1) & 1];
        if (hop < 9) {
            agg_kernel<false><<<(HALF + 255) / 256, 256, 0, stream>>>(
                in, ell16, cnt4, norm, h0s, out, nullptr);
        } else {
            agg_kernel<true><<<(HALF + 255) / 256, 256, 0, stream>>>(
                in, ell16, cnt4, norm, h0s, nullptr, (float4*)r_out);
        }
    }

    ffn_kernel<<<(N + FNB - 1) / FNB, 256, 0, stream>>>(
        r_out, feat, w1, b1, w2, b2, rst);
}

// Round 6
// 522.101 us; speedup vs baseline: 1.4818x; 1.0047x over previous
//
#include <hip/hip_runtime.h>

// APPNP block: 10 hops of symmetric-normalized propagation + FFN + residual.
// Round 14: build v4 + ffn v3 unchanged (both out of top-5; ffn fix landed).
// AGG v2: old fused 2-node version was latency-bound (41.7us/hop, occupancy
// 38%, VALUBusy 22%, no pipe saturated): ~16 serial idx->gather rounds per
// thread, only 4 loads in flight, grid 1172 blocks = 18 waves/CU.
// Now: 1 (node,chunk) per thread (600k thr, 2344 blocks -> ~2x waves/CU);
// all 4 buckets' first-8 indices hoisted as four uint4 loads (one latency
// round); gathers split into a predicated LOAD chain (8 in flight, no
// intervening waits) + predicated ADD chain; scalar tail for deg>8 (~2%).
// Bucket-phase ordering preserved for L2 locality.

constexpr int N      = 100000;
constexpr int E      = 1600000;
constexpr int D      = 48;     // floats per node
constexpr int D4     = 12;     // float4 per node
constexpr int C8     = 6;      // chunks of 8 bf16 (16B) per node
constexpr int NB     = 4;      // source buckets, width 25000
constexpr int BW     = 25000;  // bucket width (fits ushort local ids)
constexpr int BCAP   = 24;     // per-(node,bucket) cap; P(Bin(deg,1/4)>24) ~ 1e-8
constexpr int FNB    = 64;     // ffn nodes per block (256 thr = 64 nodes x 4 chunks)
constexpr int HP     = 49;     // padded LDS row stride (odd -> bank-conflict-free)
constexpr int WNODES = 250;    // nodes per window
constexpr int NWIN   = N / WNODES;   // 400 windows
constexpr int WCAP   = 5120;   // edges per window bin (mean 4000, sd 63 -> +17.8 sd)
constexpr int TILE   = 8192;   // edges per multisplit tile

typedef unsigned int uint;
typedef unsigned short ushort_t;
typedef uint  __attribute__((ext_vector_type(4))) nuint4;
typedef float __attribute__((ext_vector_type(4))) nfloat4;

__device__ __forceinline__ uint pack_bf16x2(float x, float y) {
    uint bx = __float_as_uint(x), by = __float_as_uint(y);
    bx = (bx + 0x7FFFu + ((bx >> 16) & 1u)) >> 16;          // RNE
    by = (by + 0x7FFFu + ((by >> 16) & 1u)) >> 16;
    return bx | (by << 16);
}

__device__ __forceinline__ void unpack_add(uint u, float& a0, float& a1) {
    a0 += __uint_as_float(u << 16);
    a1 += __uint_as_float(u & 0xFFFF0000u);
}

__global__ __launch_bounds__(256) void zero_kernel(int* __restrict__ tails) {
    int i = blockIdx.x * 256 + threadIdx.x;
    if (i < NWIN) tails[i] = 0;
}

// Phase A: 400-way LDS multisplit. Each block owns a tile of 8192 edges:
// stage packed (s<<9|dl) + window id in LDS, histogram windows (LDS atomics),
// reserve contiguous per-window space in the global bins (one atomicAdd per
// (tile,window)), then scatter from LDS.
__global__ __launch_bounds__(256) void bin_scan_kernel(const int* __restrict__ src,
                                                       const int* __restrict__ dst,
                                                       uint* __restrict__ bins,
                                                       int* __restrict__ tails) {
    __shared__ uint     se[TILE];       // packed edge: s<<9 | d_local   (32KB)
    __shared__ ushort_t sw[TILE];       // window id, 0xFFFF = invalid   (16KB)
    __shared__ int      hcnt[NWIN];     // histogram, then rank counter  (1.6KB)
    __shared__ int      hbase[NWIN];    // reserved global base          (1.6KB)

    int tid = threadIdx.x;
    int e0  = blockIdx.x * TILE;

    for (int w = tid; w < NWIN; w += 256) hcnt[w] = 0;
    __syncthreads();

    for (int i = tid; i < TILE; i += 256) {
        int e = e0 + i;
        if (e < E) {
            int d = dst[e];
            int s = src[e];
            int wid = (uint)d / (uint)WNODES;       // magic mul
            int dl  = d - wid * WNODES;             // 0..249 (9 bits)
            se[i] = ((uint)s << 9) | (uint)dl;
            sw[i] = (ushort_t)wid;
            atomicAdd(&hcnt[wid], 1);
        } else {
            sw[i] = 0xFFFFu;
        }
    }
    __syncthreads();

    for (int w = tid; w < NWIN; w += 256) {
        int c = hcnt[w];
        hbase[w] = c ? atomicAdd(&tails[w], c) : 0;
        hcnt[w] = 0;                                // reuse as rank counter
    }
    __syncthreads();

    for (int i = tid; i < TILE; i += 256) {
        uint wid = sw[i];
        if (wid == 0xFFFFu) continue;
        int rank = atomicAdd(&hcnt[wid], 1);
        int pos  = hbase[wid] + rank;
        if (pos < WCAP) bins[(size_t)wid * WCAP + pos] = se[i];
    }
}

// Phase B: block w reads ONLY its window's contiguous bin (~4000 edges),
// accumulates the 250-node ELL slice + counts in LDS, writes back coalesced.
__global__ __launch_bounds__(256) void build_window_kernel(const uint* __restrict__ bins,
                                                           const int* __restrict__ tails,
                                                           int* __restrict__ cnt4,
                                                           ushort_t* __restrict__ ell16) {
    __shared__ int lcnt[WNODES * NB];                       //  4000 B
    __shared__ __align__(16) ushort_t lell[WNODES * NB * BCAP];  // 48000 B

    int w   = blockIdx.x;
    int tid = threadIdx.x;

    for (int i = tid; i < WNODES * NB; i += 256) lcnt[i] = 0;
    __syncthreads();

    int cnt = tails[w];
    if (cnt > WCAP) cnt = WCAP;
    const uint* bs = bins + (size_t)w * WCAP;
    for (int i = tid; i < cnt; i += 256) {
        uint u = bs[i];
        int dl = (int)(u & 0x1FFu);
        int s  = (int)(u >> 9);
        int b = (s >= BW) + (s >= 2 * BW) + (s >= 3 * BW);
        int lidx = dl * NB + b;
        int cpos = atomicAdd(&lcnt[lidx], 1);
        if (cpos < BCAP) lell[lidx * BCAP + cpos] = (ushort_t)(s - b * BW);
    }
    __syncthreads();

    int nbase = w * WNODES;
    int* gcnt = cnt4 + (size_t)nbase * NB;
    for (int i = tid; i < WNODES * NB; i += 256) gcnt[i] = lcnt[i];
    const uint4* l4 = (const uint4*)lell;
    uint4* g4 = (uint4*)(ell16 + (size_t)nbase * NB * BCAP);
    constexpr int NV4 = WNODES * NB * BCAP * 2 / 16;        // 3000
    for (int i = tid; i < NV4; i += 256)
        __builtin_nontemporal_store(*(const nuint4*)&l4[i], (nuint4*)&g4[i]);
}

// scaled0 = feat*norm (bf16, node-major 96B rows) and h0s = 0.1*feat (bf16).
__global__ __launch_bounds__(256) void norm_scaled0_kernel(const int* __restrict__ cnt4,
                                                           const float4* __restrict__ feat,
                                                           float* __restrict__ norm,
                                                           uint4* __restrict__ sA,
                                                           uint4* __restrict__ h0s) {
    int t = blockIdx.x * 256 + threadIdx.x;
    if (t >= N * C8) return;
    int n = t / C8;
    int c = t - n * C8;
    int4 cc = *(const int4*)(cnt4 + n * NB);
    float dg = (float)(cc.x + cc.y + cc.z + cc.w);
    float nm = 1.0f / sqrtf(fmaxf(dg, 1.0f));
    if (c == 0) norm[n] = nm;
    float4 v0 = feat[n * D4 + c * 2];
    float4 v1 = feat[n * D4 + c * 2 + 1];
    uint4 o;
    o.x = pack_bf16x2(v0.x * nm, v0.y * nm);
    o.y = pack_bf16x2(v0.z * nm, v0.w * nm);
    o.z = pack_bf16x2(v1.x * nm, v1.y * nm);
    o.w = pack_bf16x2(v1.z * nm, v1.w * nm);
    sA[t] = o;
    uint4 h;
    h.x = pack_bf16x2(v0.x * 0.1f, v0.y * 0.1f);
    h.y = pack_bf16x2(v0.z * 0.1f, v0.w * 0.1f);
    h.z = pack_bf16x2(v1.x * 0.1f, v1.y * 0.1f);
    h.w = pack_bf16x2(v1.z * 0.1f, v1.w * 0.1f);
    h0s[t] = h;
}

// AGG v2: thread i owns (n = i/6, c = i%6). 600k threads, 2344 blocks.
// All 4 buckets' first-8 ELL indices hoisted as uint4 loads; per bucket a
// predicated 8-deep gather chain (loads separated from adds -> all 8 issue
// before any wait), scalar tail for deg>8. 6 consecutive lanes read one
// source node's contiguous 96B bf16 row (coalesced).
template <bool LAST>
__global__ __launch_bounds__(256) void agg_kernel(const uint4* __restrict__ scaled_in,
                                                  const ushort_t* __restrict__ ell16,
                                                  const int* __restrict__ cnt4,
                                                  const float* __restrict__ norm,
                                                  const uint4* __restrict__ h0s,
                                                  uint4* __restrict__ scaled_out,
                                                  float4* __restrict__ h_out) {
    int i = blockIdx.x * 256 + threadIdx.x;
    if (i >= N * C8) return;
    int n = i / C8;
    int c = i - n * C8;

    int4 cc = *(const int4*)(cnt4 + n * NB);
    int cb[NB] = {min(cc.x, BCAP), min(cc.y, BCAP), min(cc.z, BCAP), min(cc.w, BCAP)};
    float nm = norm[n];
    const ushort_t* row0 = ell16 + (size_t)n * (NB * BCAP);

    // hoist all 4 buckets' first-8 indices (16B aligned: 48B bucket stride)
    uint4 iv[NB];
#pragma unroll
    for (int p = 0; p < NB; ++p) iv[p] = *(const uint4*)(row0 + p * BCAP);

    float a[8] = {0.f, 0.f, 0.f, 0.f, 0.f, 0.f, 0.f, 0.f};

    auto addv = [&](uint4 v) {
        unpack_add(v.x, a[0], a[1]); unpack_add(v.y, a[2], a[3]);
        unpack_add(v.z, a[4], a[5]); unpack_add(v.w, a[6], a[7]);
    };

#pragma unroll
    for (int p = 0; p < NB; ++p) {
        const uint4* base = scaled_in + (size_t)p * (BW * C8) + c;
        int cnt = cb[p];
        uint s[8];
        s[0] = iv[p].x & 0xFFFFu; s[1] = iv[p].x >> 16;
        s[2] = iv[p].y & 0xFFFFu; s[3] = iv[p].y >> 16;
        s[4] = iv[p].z & 0xFFFFu; s[5] = iv[p].z >> 16;
        s[6] = iv[p].w & 0xFFFFu; s[7] = iv[p].w >> 16;
        uint4 v[8];
#pragma unroll
        for (int jj = 0; jj < 8; ++jj)
            if (jj < cnt) v[jj] = base[s[jj] * C8];     // loads only, no waits
#pragma unroll
        for (int jj = 0; jj < 8; ++jj)
            if (jj < cnt) addv(v[jj]);                  // waits amortized here
        for (int j = 8; j < cnt; ++j)                   // rare tail (P ~ 2%)
            addv(base[row0[p * BCAP + j] * C8]);
    }

    // finish: h = 0.9*nm*agg + 0.1*h0
    nuint4 hs = __builtin_nontemporal_load((const nuint4*)&h0s[i]);
    float rr[8] = {0.f, 0.f, 0.f, 0.f, 0.f, 0.f, 0.f, 0.f};
    unpack_add(hs.x, rr[0], rr[1]); unpack_add(hs.y, rr[2], rr[3]);
    unpack_add(hs.z, rr[4], rr[5]); unpack_add(hs.w, rr[6], rr[7]);
    float sc = 0.9f * nm;
    float hv[8];
#pragma unroll
    for (int k = 0; k < 8; ++k) hv[k] = fmaf(sc, a[k], rr[k]);
    if (LAST) {
        nfloat4 o0 = {hv[0], hv[1], hv[2], hv[3]};
        nfloat4 o1 = {hv[4], hv[5], hv[6], hv[7]};
        __builtin_nontemporal_store(o0, (nfloat4*)&h_out[n * D4 + c * 2]);
        __builtin_nontemporal_store(o1, (nfloat4*)&h_out[n * D4 + c * 2 + 1]);
    } else {
        nuint4 o;
        o.x = pack_bf16x2(hv[0] * nm, hv[1] * nm);
        o.y = pack_bf16x2(hv[2] * nm, hv[3] * nm);
        o.z = pack_bf16x2(hv[4] * nm, hv[5] * nm);
        o.w = pack_bf16x2(hv[6] * nm, hv[7] * nm);
        __builtin_nontemporal_store(o, (nuint4*)&scaled_out[i]);
    }
}

// rst = relu(h@w1 + b1)@w2 + b2 + features.  (R4 version, 4 thr/node,
// weights in LDS: wave-uniform broadcast ds_read_b128, conflict-free.)
__global__ __launch_bounds__(256) void ffn_kernel(const float* __restrict__ r,
                                                  const float* __restrict__ feat,
                                                  const float* __restrict__ w1,
                                                  const float* __restrict__ b1,
                                                  const float* __restrict__ w2,
                                                  const float* __restrict__ b2,
                                                  float* __restrict__ rst) {
    __shared__ __align__(16) float sw1[D * D];   // 9216 B
    __shared__ __align__(16) float sw2[D * D];   // 9216 B
    __shared__ float sb[2 * D];                  //  384 B
    __shared__ float sh[FNB * HP];               // 12544 B  (h tile, reused for hid)

    int tid = threadIdx.x;
    for (int i = tid; i < D * D; i += 256) {
        sw1[i] = w1[i];
        sw2[i] = w2[i];
    }
    if (tid < D) {
        sb[tid] = b1[tid];
        sb[D + tid] = b2[tid];
    }

    int nb = blockIdx.x * FNB;
    const float4* r4 = (const float4*)r + (size_t)nb * D4;
    int maxf4 = (N - nb) * D4;
    if (maxf4 > FNB * D4) maxf4 = FNB * D4;
    for (int f = tid; f < maxf4; f += 256) {
        float4 v = r4[f];
        int row = f / D4;
        int col = (f - row * D4) * 4;
        float* dp = sh + row * HP + col;
        dp[0] = v.x; dp[1] = v.y; dp[2] = v.z; dp[3] = v.w;
    }
    __syncthreads();

    int n_local = tid & 63;
    int co = __builtin_amdgcn_readfirstlane((tid >> 6) * 12);   // wave-uniform
    int node = nb + n_local;
    bool alive = node < N;
    const float* hrow = sh + n_local * HP;

    float acc[12];
#pragma unroll
    for (int j = 0; j < 12; ++j) acc[j] = sb[co + j];
#pragma unroll
    for (int k = 0; k < D; ++k) {
        float hk = hrow[k];
        const float4* wr = (const float4*)(sw1 + k * D + co);
#pragma unroll
        for (int jc = 0; jc < 3; ++jc) {
            float4 wv = wr[jc];
            acc[4 * jc + 0] = fmaf(hk, wv.x, acc[4 * jc + 0]);
            acc[4 * jc + 1] = fmaf(hk, wv.y, acc[4 * jc + 1]);
            acc[4 * jc + 2] = fmaf(hk, wv.z, acc[4 * jc + 2]);
            acc[4 * jc + 3] = fmaf(hk, wv.w, acc[4 * jc + 3]);
        }
    }
#pragma unroll
    for (int j = 0; j < 12; ++j) acc[j] = fmaxf(acc[j], 0.0f);
    __syncthreads();                    // everyone done reading h tile
    {
        float* hw = sh + n_local * HP + co;
#pragma unroll
        for (int j = 0; j < 12; ++j) hw[j] = acc[j];
    }
    __syncthreads();                    // hid tile ready
#pragma unroll
    for (int j = 0; j < 12; ++j) acc[j] = sb[D + co + j];
#pragma unroll
    for (int k = 0; k < D; ++k) {
        float hk = hrow[k];
        const float4* wr = (const float4*)(sw2 + k * D + co);
#pragma unroll
        for (int jc = 0; jc < 3; ++jc) {
            float4 wv = wr[jc];
            acc[4 * jc + 0] = fmaf(hk, wv.x, acc[4 * jc + 0]);
            acc[4 * jc + 1] = fmaf(hk, wv.y, acc[4 * jc + 1]);
            acc[4 * jc + 2] = fmaf(hk, wv.z, acc[4 * jc + 2]);
            acc[4 * jc + 3] = fmaf(hk, wv.w, acc[4 * jc + 3]);
        }
    }
    if (alive) {
        const float4* f4 = (const float4*)feat + (size_t)node * D4 + (co / 4);
        float4*       o4 = (float4*)rst + (size_t)node * D4 + (co / 4);
#pragma unroll
        for (int jc = 0; jc < 3; ++jc) {
            float4 fv = f4[jc];
            float4 o;
            o.x = acc[4 * jc + 0] + fv.x;
            o.y = acc[4 * jc + 1] + fv.y;
            o.z = acc[4 * jc + 2] + fv.z;
            o.w = acc[4 * jc + 3] + fv.w;
            o4[jc] = o;
        }
    }
}

extern "C" void kernel_launch(void* const* d_in, const int* in_sizes, int n_in,
                              void* d_out, int out_size, void* d_ws, size_t ws_size,
                              hipStream_t stream) {
    const float* feat = (const float*)d_in[0];
    const int*   src  = (const int*)d_in[1];
    const int*   dst  = (const int*)d_in[2];
    const float* w1   = (const float*)d_in[3];
    const float* b1   = (const float*)d_in[4];
    const float* w2   = (const float*)d_in[5];
    const float* b2   = (const float*)d_in[6];

    float* rst   = (float*)d_out;                  // output 0: [N, D]
    float* r_out = rst + (size_t)N * D;            // output 1: [N, D]

    // workspace layout (16B-aligned offsets)
    char*     w     = (char*)d_ws;
    int*      cnt4  = (int*)w;                               //  1,600,000 B
    float*    norm  = (float*)(w + 1600000);                 //    400,000 B
    ushort_t* ell16 = (ushort_t*)(w + 2000000);              // 19,200,000 B
    uint4*    sA    = (uint4*)(w + 2000000 + 19200000);      //  9,600,000 B
    uint4*    sB    = sA + (size_t)N * C8;                   //  9,600,000 B
    uint4*    h0s   = sB + (size_t)N * C8;                   //  9,600,000 B
    // build-phase scratch, dead before sA/sB are first written:
    uint*     bins  = (uint*)sA;                             //  8,192,000 B (aliases sA)
    int*      tails = (int*)sB;                              //      1,600 B (aliases sB)

    zero_kernel<<<(NWIN + 255) / 256, 256, 0, stream>>>(tails);
    bin_scan_kernel<<<(E + TILE - 1) / TILE, 256, 0, stream>>>(src, dst, bins, tails);
    build_window_kernel<<<NWIN, 256, 0, stream>>>(bins, tails, cnt4, ell16);
    norm_scaled0_kernel<<<(N * C8 + 255) / 256, 256, 0, stream>>>(
        cnt4, (const float4*)feat, norm, sA, h0s);

    uint4* bufs[2] = {sA, sB};
    for (int hop = 0; hop < 10; ++hop) {
        const uint4* in  = bufs[hop & 1];
        uint4*       out = bufs[(hop + 1) & 1];
        if (hop < 9) {
            agg_kernel<false><<<(N * C8 + 255) / 256, 256, 0, stream>>>(
                in, ell16, cnt4, norm, h0s, out, nullptr);
        } else {
            agg_kernel<true><<<(N * C8 + 255) / 256, 256, 0, stream>>>(
                in, ell16, cnt4, norm, h0s, nullptr, (float4*)r_out);
        }
    }

    ffn_kernel<<<(N + FNB - 1) / FNB, 256, 0, stream>>>(
        r_out, feat, w1, b1, w2, b2, rst);
}

// Round 7
// 477.066 us; speedup vs baseline: 1.6217x; 1.0944x over previous
//
#include <hip/hip_runtime.h>

// APPNP block: 10 hops of symmetric-normalized propagation + FFN + residual.
// Round 15: ffn v3 + bin_scan multisplit kept. AGG v3 traffic diet:
// R5's MLP boost was NEUTRAL -> agg is random-access-BW bound (~1.8 TB/s on
// 68 MB/hop), so cut bytes: unified compact ELL row (112 B/node = header
// {norm f32, 4 stored counts} + <=52 bucket-concatenated ushort local ids)
// replaces padded ELL(192B) + cnt4(16B) + norm(4B) reads. Rows are staged
// per-block into LDS (42 rows, 4.6KB) -> dynamic entry indexing happens in
// LDS (no scratch), and the 6x per-lane ELL redundancy disappears.
// True in-degree still used for norm; per-bucket cap 24 unchanged; unified
// cap 52 adds P~1e-11/node of a dropped edge (same class as before).
// Build windows shrink to 128 nodes so build_window compacts rows in LDS
// (41KB) and writes them coalesced. Workspace 50 -> 42 MB.

constexpr int N      = 100000;
constexpr int E      = 1600000;
constexpr int D      = 48;     // floats per node
constexpr int D4     = 12;     // float4 per node
constexpr int C8     = 6;      // chunks of 8 bf16 (16B) per node
constexpr int NB     = 4;      // source buckets, width 25000
constexpr int BW     = 25000;  // bucket width (fits ushort local ids)
constexpr int BCAP   = 24;     // per-(node,bucket) cap in build LDS
constexpr int ECAP   = 52;     // unified per-node entry cap (P(Pois16>=53)~1e-11)
constexpr int RS     = 56;     // ushorts per compact row (4 hdr + 52 entries) = 112B
constexpr int RU     = 28;     // uints per row
constexpr int RV     = 7;      // uint4 per row
constexpr int FNB    = 64;     // ffn nodes per block
constexpr int HP     = 49;     // ffn LDS row stride
constexpr int WN     = 128;    // build window nodes (pow2 -> shift binning)
constexpr int NWIN   = (N + WN - 1) / WN;   // 782
constexpr int NPADR  = NWIN * WN;           // padded row count (100096)
constexpr int WCAP   = 2560;   // edges per window bin (mean 2046, +11 sd)
constexpr int TILE   = 8192;   // edges per multisplit tile
constexpr int ANB    = 42;     // agg nodes per block (42*6=252 threads)

typedef unsigned int uint;
typedef unsigned short ushort_t;
typedef uint  __attribute__((ext_vector_type(4))) nuint4;
typedef float __attribute__((ext_vector_type(4))) nfloat4;

__device__ __forceinline__ uint pack_bf16x2(float x, float y) {
    uint bx = __float_as_uint(x), by = __float_as_uint(y);
    bx = (bx + 0x7FFFu + ((bx >> 16) & 1u)) >> 16;          // RNE
    by = (by + 0x7FFFu + ((by >> 16) & 1u)) >> 16;
    return bx | (by << 16);
}

__device__ __forceinline__ void unpack_add(uint u, float& a0, float& a1) {
    a0 += __uint_as_float(u << 16);
    a1 += __uint_as_float(u & 0xFFFF0000u);
}

__global__ __launch_bounds__(256) void zero_kernel(int* __restrict__ tails) {
    int i = blockIdx.x * 256 + threadIdx.x;
    if (i < NWIN) tails[i] = 0;
}

// Phase A: NWIN-way LDS multisplit (window = 128 dst nodes -> shift/mask).
// Stage packed (s<<7|dl) + window id in LDS, histogram (LDS atomics),
// reserve contiguous bin space (one global atomic per tile,window), scatter.
__global__ __launch_bounds__(256) void bin_scan_kernel(const int* __restrict__ src,
                                                       const int* __restrict__ dst,
                                                       uint* __restrict__ bins,
                                                       int* __restrict__ tails) {
    __shared__ uint     se[TILE];       // packed edge: s<<7 | d_local   (32KB)
    __shared__ ushort_t sw[TILE];       // window id, 0xFFFF = invalid   (16KB)
    __shared__ int      hcnt[NWIN];     // histogram, then rank counter  (3.1KB)
    __shared__ int      hbase[NWIN];    // reserved global base          (3.1KB)

    int tid = threadIdx.x;
    int e0  = blockIdx.x * TILE;

    for (int w = tid; w < NWIN; w += 256) hcnt[w] = 0;
    __syncthreads();

    for (int i = tid; i < TILE; i += 256) {
        int e = e0 + i;
        if (e < E) {
            int d = dst[e];
            int s = src[e];
            int wid = d >> 7;                       // WN = 128
            int dl  = d & (WN - 1);
            se[i] = ((uint)s << 7) | (uint)dl;
            sw[i] = (ushort_t)wid;
            atomicAdd(&hcnt[wid], 1);
        } else {
            sw[i] = 0xFFFFu;
        }
    }
    __syncthreads();

    for (int w = tid; w < NWIN; w += 256) {
        int c = hcnt[w];
        hbase[w] = c ? atomicAdd(&tails[w], c) : 0;
        hcnt[w] = 0;                                // reuse as rank counter
    }
    __syncthreads();

    for (int i = tid; i < TILE; i += 256) {
        uint wid = sw[i];
        if (wid == 0xFFFFu) continue;
        int rank = atomicAdd(&hcnt[wid], 1);
        int pos  = hbase[wid] + rank;
        if (pos < WCAP) bins[(size_t)wid * WCAP + pos] = se[i];
    }
}

// Phase B: block w reads its window's contiguous bin (~2046 edges),
// accumulates per-(node,bucket) slots in LDS, then COMPACTS each node into
// a 112B unified row {norm f32, 4 uchar stored counts, <=52 ushort entries}
// and writes rows + cnt4 back coalesced. True degree (uncapped) -> norm.
__global__ __launch_bounds__(256) void build_window_kernel(const uint* __restrict__ bins,
                                                           const int* __restrict__ tails,
                                                           int* __restrict__ cnt4,
                                                           ushort_t* __restrict__ ellc) {
    __shared__ int lcnt[WN * NB];                            //  2048 B
    __shared__ ushort_t lell[WN * NB * BCAP];                // 24576 B
    __shared__ __align__(16) ushort_t lrow[WN * RS];         // 14336 B

    int w   = blockIdx.x;
    int tid = threadIdx.x;

    for (int i = tid; i < WN * NB; i += 256) lcnt[i] = 0;
    __syncthreads();

    int cnt = tails[w];
    if (cnt > WCAP) cnt = WCAP;
    const uint* bs = bins + (size_t)w * WCAP;
    for (int i = tid; i < cnt; i += 256) {
        uint u = bs[i];
        int dl = (int)(u & (WN - 1));
        int s  = (int)(u >> 7);
        int b = (s >= BW) + (s >= 2 * BW) + (s >= 3 * BW);
        int lidx = dl * NB + b;
        int cpos = atomicAdd(&lcnt[lidx], 1);
        if (cpos < BCAP) lell[lidx * BCAP + cpos] = (ushort_t)(s - b * BW);
    }
    __syncthreads();

    // compact: one thread per node
    if (tid < WN) {
        int node = w * WN + tid;
        ushort_t* r = lrow + tid * RS;
        if (node < N) {
            int c0 = lcnt[tid * NB + 0], c1 = lcnt[tid * NB + 1];
            int c2 = lcnt[tid * NB + 2], c3 = lcnt[tid * NB + 3];
            float dg = (float)(c0 + c1 + c2 + c3);
            float nm = 1.0f / sqrtf(fmaxf(dg, 1.0f));
            int rem = ECAP;
            int t0 = min(min(c0, BCAP), rem); rem -= t0;
            int t1 = min(min(c1, BCAP), rem); rem -= t1;
            int t2 = min(min(c2, BCAP), rem); rem -= t2;
            int t3 = min(min(c3, BCAP), rem);
            uint nmb = __float_as_uint(nm);
            r[0] = (ushort_t)(nmb & 0xFFFFu);
            r[1] = (ushort_t)(nmb >> 16);
            r[2] = (ushort_t)(t0 | (t1 << 8));
            r[3] = (ushort_t)(t2 | (t3 << 8));
            int o = 4;
            for (int j = 0; j < t0; ++j) r[o++] = lell[(tid * NB + 0) * BCAP + j];
            for (int j = 0; j < t1; ++j) r[o++] = lell[(tid * NB + 1) * BCAP + j];
            for (int j = 0; j < t2; ++j) r[o++] = lell[(tid * NB + 2) * BCAP + j];
            for (int j = 0; j < t3; ++j) r[o++] = lell[(tid * NB + 3) * BCAP + j];
            while (o < RS) r[o++] = 0;
        } else {
            for (int o = 0; o < RS; ++o) r[o] = 0;
        }
    }
    __syncthreads();

    int nbase = w * WN;
    for (int i = tid; i < WN * NB; i += 256) {
        if (nbase + i / NB < N) cnt4[(size_t)nbase * NB + i] = lcnt[i];
    }
    const uint4* l4 = (const uint4*)lrow;
    uint4* g4 = (uint4*)(ellc + (size_t)nbase * RS);
    for (int i = tid; i < WN * RV; i += 256)
        __builtin_nontemporal_store(*(const nuint4*)&l4[i], (nuint4*)&g4[i]);
}

// scaled0 = feat*norm (bf16, node-major 96B rows) and h0s = 0.1*feat (bf16).
__global__ __launch_bounds__(256) void norm_scaled0_kernel(const int* __restrict__ cnt4,
                                                           const float4* __restrict__ feat,
                                                           uint4* __restrict__ sA,
                                                           uint4* __restrict__ h0s) {
    int t = blockIdx.x * 256 + threadIdx.x;
    if (t >= N * C8) return;
    int n = t / C8;
    int c = t - n * C8;
    int4 cc = *(const int4*)(cnt4 + n * NB);
    float dg = (float)(cc.x + cc.y + cc.z + cc.w);
    float nm = 1.0f / sqrtf(fmaxf(dg, 1.0f));
    float4 v0 = feat[n * D4 + c * 2];
    float4 v1 = feat[n * D4 + c * 2 + 1];
    uint4 o;
    o.x = pack_bf16x2(v0.x * nm, v0.y * nm);
    o.y = pack_bf16x2(v0.z * nm, v0.w * nm);
    o.z = pack_bf16x2(v1.x * nm, v1.y * nm);
    o.w = pack_bf16x2(v1.z * nm, v1.w * nm);
    sA[t] = o;
    uint4 h;
    h.x = pack_bf16x2(v0.x * 0.1f, v0.y * 0.1f);
    h.y = pack_bf16x2(v0.z * 0.1f, v0.w * 0.1f);
    h.z = pack_bf16x2(v1.x * 0.1f, v1.y * 0.1f);
    h.w = pack_bf16x2(v1.z * 0.1f, v1.w * 0.1f);
    h0s[t] = h;
}

// AGG v3: block = 42 nodes x 6 chunks (252 active threads). Compact rows
// staged cooperatively into LDS (294 uint4, coalesced); entry indices read
// from LDS (dynamic addressing, no scratch); norm from row header (no cnt4/
// norm stream). Gathers keep the v2 split predicated 8-deep chain per bucket.
template <bool LAST>
__global__ __launch_bounds__(256) void agg_kernel(const uint4* __restrict__ scaled_in,
                                                  const uint4* __restrict__ ellc4,
                                                  const uint4* __restrict__ h0s,
                                                  uint4* __restrict__ scaled_out,
                                                  float4* __restrict__ h_out) {
    __shared__ uint4 srow[ANB * RV];    // 42 rows x 112B = 4704 B

    int tid = threadIdx.x;
    int nb  = blockIdx.x * ANB;
    {
        size_t gbase = (size_t)nb * RV;
        for (int f = tid; f < ANB * RV; f += 256) {
            size_t g = gbase + f;
            if (g < (size_t)NPADR * RV) srow[f] = ellc4[g];
        }
    }
    __syncthreads();

    int ln = tid / C8;
    int c  = tid - ln * C8;
    int n  = nb + ln;
    if (tid >= ANB * C8 || n >= N) return;

    const uint*     su  = (const uint*)srow;
    const ushort_t* s16 = (const ushort_t*)srow;
    float nm = __uint_as_float(su[ln * RU]);
    uint  w1 = su[ln * RU + 1];
    int sc[NB] = {(int)(w1 & 255u), (int)((w1 >> 8) & 255u),
                  (int)((w1 >> 16) & 255u), (int)(w1 >> 24)};
    int ebase = ln * RS + 4;

    float a[8] = {0.f, 0.f, 0.f, 0.f, 0.f, 0.f, 0.f, 0.f};
    auto addv = [&](uint4 v) {
        unpack_add(v.x, a[0], a[1]); unpack_add(v.y, a[2], a[3]);
        unpack_add(v.z, a[4], a[5]); unpack_add(v.w, a[6], a[7]);
    };

    int o = 0;
#pragma unroll
    for (int p = 0; p < NB; ++p) {
        const uint4* base = scaled_in + (size_t)p * (BW * C8) + c;
        int cnt = sc[p];
        uint s8[8];
        uint4 v[8];
#pragma unroll
        for (int jj = 0; jj < 8; ++jj)
            if (jj < cnt) s8[jj] = s16[ebase + o + jj];
#pragma unroll
        for (int jj = 0; jj < 8; ++jj)
            if (jj < cnt) v[jj] = base[s8[jj] * C8];    // loads issue together
#pragma unroll
        for (int jj = 0; jj < 8; ++jj)
            if (jj < cnt) addv(v[jj]);
        for (int j = 8; j < cnt; ++j)                   // rare tail
            addv(base[s16[ebase + o + j] * C8]);
        o += cnt;
    }

    int t = n * C8 + c;
    nuint4 hs = __builtin_nontemporal_load((const nuint4*)&h0s[t]);
    float rr[8] = {0.f, 0.f, 0.f, 0.f, 0.f, 0.f, 0.f, 0.f};
    unpack_add(hs.x, rr[0], rr[1]); unpack_add(hs.y, rr[2], rr[3]);
    unpack_add(hs.z, rr[4], rr[5]); unpack_add(hs.w, rr[6], rr[7]);
    float scn = 0.9f * nm;
    float hv[8];
#pragma unroll
    for (int k = 0; k < 8; ++k) hv[k] = fmaf(scn, a[k], rr[k]);
    if (LAST) {
        nfloat4 o0 = {hv[0], hv[1], hv[2], hv[3]};
        nfloat4 o1 = {hv[4], hv[5], hv[6], hv[7]};
        __builtin_nontemporal_store(o0, (nfloat4*)&h_out[n * D4 + c * 2]);
        __builtin_nontemporal_store(o1, (nfloat4*)&h_out[n * D4 + c * 2 + 1]);
    } else {
        nuint4 ov;
        ov.x = pack_bf16x2(hv[0] * nm, hv[1] * nm);
        ov.y = pack_bf16x2(hv[2] * nm, hv[3] * nm);
        ov.z = pack_bf16x2(hv[4] * nm, hv[5] * nm);
        ov.w = pack_bf16x2(hv[6] * nm, hv[7] * nm);
        __builtin_nontemporal_store(ov, (nuint4*)&scaled_out[t]);
    }
}

// rst = relu(h@w1 + b1)@w2 + b2 + features.  (R4 version, 4 thr/node,
// weights in LDS: wave-uniform broadcast ds_read_b128, conflict-free.)
__global__ __launch_bounds__(256) void ffn_kernel(const float* __restrict__ r,
                                                  const float* __restrict__ feat,
                                                  const float* __restrict__ w1,
                                                  const float* __restrict__ b1,
                                                  const float* __restrict__ w2,
                                                  const float* __restrict__ b2,
                                                  float* __restrict__ rst) {
    __shared__ __align__(16) float sw1[D * D];   // 9216 B
    __shared__ __align__(16) float sw2[D * D];   // 9216 B
    __shared__ float sb[2 * D];                  //  384 B
    __shared__ float sh[FNB * HP];               // 12544 B

    int tid = threadIdx.x;
    for (int i = tid; i < D * D; i += 256) {
        sw1[i] = w1[i];
        sw2[i] = w2[i];
    }
    if (tid < D) {
        sb[tid] = b1[tid];
        sb[D + tid] = b2[tid];
    }

    int nb = blockIdx.x * FNB;
    const float4* r4 = (const float4*)r + (size_t)nb * D4;
    int maxf4 = (N - nb) * D4;
    if (maxf4 > FNB * D4) maxf4 = FNB * D4;
    for (int f = tid; f < maxf4; f += 256) {
        float4 v = r4[f];
        int row = f / D4;
        int col = (f - row * D4) * 4;
        float* dp = sh + row * HP + col;
        dp[0] = v.x; dp[1] = v.y; dp[2] = v.z; dp[3] = v.w;
    }
    __syncthreads();

    int n_local = tid & 63;
    int co = __builtin_amdgcn_readfirstlane((tid >> 6) * 12);   // wave-uniform
    int node = nb + n_local;
    bool alive = node < N;
    const float* hrow = sh + n_local * HP;

    float acc[12];
#pragma unroll
    for (int j = 0; j < 12; ++j) acc[j] = sb[co + j];
#pragma unroll
    for (int k = 0; k < D; ++k) {
        float hk = hrow[k];
        const float4* wr = (const float4*)(sw1 + k * D + co);
#pragma unroll
        for (int jc = 0; jc < 3; ++jc) {
            float4 wv = wr[jc];
            acc[4 * jc + 0] = fmaf(hk, wv.x, acc[4 * jc + 0]);
            acc[4 * jc + 1] = fmaf(hk, wv.y, acc[4 * jc + 1]);
            acc[4 * jc + 2] = fmaf(hk, wv.z, acc[4 * jc + 2]);
            acc[4 * jc + 3] = fmaf(hk, wv.w, acc[4 * jc + 3]);
        }
    }
#pragma unroll
    for (int j = 0; j < 12; ++j) acc[j] = fmaxf(acc[j], 0.0f);
    __syncthreads();
    {
        float* hw = sh + n_local * HP + co;
#pragma unroll
        for (int j = 0; j < 12; ++j) hw[j] = acc[j];
    }
    __syncthreads();
#pragma unroll
    for (int j = 0; j < 12; ++j) acc[j] = sb[D + co + j];
#pragma unroll
    for (int k = 0; k < D; ++k) {
        float hk = hrow[k];
        const float4* wr = (const float4*)(sw2 + k * D + co);
#pragma unroll
        for (int jc = 0; jc < 3; ++jc) {
            float4 wv = wr[jc];
            acc[4 * jc + 0] = fmaf(hk, wv.x, acc[4 * jc + 0]);
            acc[4 * jc + 1] = fmaf(hk, wv.y, acc[4 * jc + 1]);
            acc[4 * jc + 2] = fmaf(hk, wv.z, acc[4 * jc + 2]);
            acc[4 * jc + 3] = fmaf(hk, wv.w, acc[4 * jc + 3]);
        }
    }
    if (alive) {
        const float4* f4 = (const float4*)feat + (size_t)node * D4 + (co / 4);
        float4*       o4 = (float4*)rst + (size_t)node * D4 + (co / 4);
#pragma unroll
        for (int jc = 0; jc < 3; ++jc) {
            float4 fv = f4[jc];
            float4 o;
            o.x = acc[4 * jc + 0] + fv.x;
            o.y = acc[4 * jc + 1] + fv.y;
            o.z = acc[4 * jc + 2] + fv.z;
            o.w = acc[4 * jc + 3] + fv.w;
            o4[jc] = o;
        }
    }
}

extern "C" void kernel_launch(void* const* d_in, const int* in_sizes, int n_in,
                              void* d_out, int out_size, void* d_ws, size_t ws_size,
                              hipStream_t stream) {
    const float* feat = (const float*)d_in[0];
    const int*   src  = (const int*)d_in[1];
    const int*   dst  = (const int*)d_in[2];
    const float* w1   = (const float*)d_in[3];
    const float* b1   = (const float*)d_in[4];
    const float* w2   = (const float*)d_in[5];
    const float* b2   = (const float*)d_in[6];

    float* rst   = (float*)d_out;                  // output 0: [N, D]
    float* r_out = rst + (size_t)N * D;            // output 1: [N, D]

    // workspace layout (16B-aligned offsets), total ~42.0 MB
    char*     w     = (char*)d_ws;
    int*      cnt4  = (int*)w;                               //  1,600,000 B
    // gap: 400,000 B (reserved)
    ushort_t* ellc  = (ushort_t*)(w + 2000000);              // 11,210,752 B (NPADR*112)
    uint4*    sA    = (uint4*)(w + 2000000 + 11210752);      //  9,600,000 B
    uint4*    sB    = sA + (size_t)N * C8;                   //  9,600,000 B
    uint4*    h0s   = sB + (size_t)N * C8;                   //  9,600,000 B
    // build-phase scratch, dead before sA/sB are first written:
    uint*     bins  = (uint*)sA;                             //  8,007,680 B (aliases sA)
    int*      tails = (int*)sB;                              //      3,128 B (aliases sB)

    zero_kernel<<<(NWIN + 255) / 256, 256, 0, stream>>>(tails);
    bin_scan_kernel<<<(E + TILE - 1) / TILE, 256, 0, stream>>>(src, dst, bins, tails);
    build_window_kernel<<<NWIN, 256, 0, stream>>>(bins, tails, cnt4, ellc);
    norm_scaled0_kernel<<<(N * C8 + 255) / 256, 256, 0, stream>>>(
        cnt4, (const float4*)feat, sA, h0s);

    uint4* bufs[2] = {sA, sB};
    int agg_grid = (N + ANB - 1) / ANB;
    for (int hop = 0; hop < 10; ++hop) {
        const uint4* in  = bufs[hop & 1];
        uint4*       out = bufs[(hop + 1) & 1];
        if (hop < 9) {
            agg_kernel<false><<<agg_grid, 256, 0, stream>>>(
                in, (const uint4*)ellc, h0s, out, nullptr);
        } else {
            agg_kernel<true><<<agg_grid, 256, 0, stream>>>(
                in, (const uint4*)ellc, h0s, nullptr, (float4*)r_out);
        }
    }

    ffn_kernel<<<(N + FNB - 1) / FNB, 256, 0, stream>>>(
        r_out, feat, w1, b1, w2, b2, rst);
}

// Round 8
// 456.237 us; speedup vs baseline: 1.6958x; 1.0457x over previous
//
#include <hip/hip_runtime.h>

// APPNP block: 10 hops of symmetric-normalized propagation + FFN + residual.
// Round 16: SINGLE CHANGE vs R15 — remove ALL nontemporal load/store hints.
// Theory: agg's entire inter-hop working set (9.6MB table + 11.2MB ellc +
// 9.6MB h0s) fits in the 256MB L3, yet mid-sequence agg showed ~58-68MB of
// HBM FETCH per hop -> L3 was not retaining. Cause: the hop loop's
// producer->consumer edges were all marked nt (scaled_out nt-stored then
// re-read by everyone next hop; h0s nt-LOADED every hop so never cached;
// ellc nt-written at build, re-read 10x; h_out nt, re-read by ffn). nt =
// stream/evict-first — exactly wrong for this reuse. Plain accesses let
// L2/L3 carry hops 2-10.
// Everything else identical to R15 (compact 112B rows, LDS row staging,
// multisplit build, ffn v3 with LDS weights).

constexpr int N      = 100000;
constexpr int E      = 1600000;
constexpr int D      = 48;     // floats per node
constexpr int D4     = 12;     // float4 per node
constexpr int C8     = 6;      // chunks of 8 bf16 (16B) per node
constexpr int NB     = 4;      // source buckets, width 25000
constexpr int BW     = 25000;  // bucket width (fits ushort local ids)
constexpr int BCAP   = 24;     // per-(node,bucket) cap in build LDS
constexpr int ECAP   = 52;     // unified per-node entry cap (P(Pois16>=53)~1e-11)
constexpr int RS     = 56;     // ushorts per compact row (4 hdr + 52 entries) = 112B
constexpr int RU     = 28;     // uints per row
constexpr int RV     = 7;      // uint4 per row
constexpr int FNB    = 64;     // ffn nodes per block
constexpr int HP     = 49;     // ffn LDS row stride
constexpr int WN     = 128;    // build window nodes (pow2 -> shift binning)
constexpr int NWIN   = (N + WN - 1) / WN;   // 782
constexpr int NPADR  = NWIN * WN;           // padded row count (100096)
constexpr int WCAP   = 2560;   // edges per window bin (mean 2046, +11 sd)
constexpr int TILE   = 8192;   // edges per multisplit tile
constexpr int ANB    = 42;     // agg nodes per block (42*6=252 threads)

typedef unsigned int uint;
typedef unsigned short ushort_t;

__device__ __forceinline__ uint pack_bf16x2(float x, float y) {
    uint bx = __float_as_uint(x), by = __float_as_uint(y);
    bx = (bx + 0x7FFFu + ((bx >> 16) & 1u)) >> 16;          // RNE
    by = (by + 0x7FFFu + ((by >> 16) & 1u)) >> 16;
    return bx | (by << 16);
}

__device__ __forceinline__ void unpack_add(uint u, float& a0, float& a1) {
    a0 += __uint_as_float(u << 16);
    a1 += __uint_as_float(u & 0xFFFF0000u);
}

__global__ __launch_bounds__(256) void zero_kernel(int* __restrict__ tails) {
    int i = blockIdx.x * 256 + threadIdx.x;
    if (i < NWIN) tails[i] = 0;
}

// Phase A: NWIN-way LDS multisplit (window = 128 dst nodes -> shift/mask).
__global__ __launch_bounds__(256) void bin_scan_kernel(const int* __restrict__ src,
                                                       const int* __restrict__ dst,
                                                       uint* __restrict__ bins,
                                                       int* __restrict__ tails) {
    __shared__ uint     se[TILE];       // packed edge: s<<7 | d_local   (32KB)
    __shared__ ushort_t sw[TILE];       // window id, 0xFFFF = invalid   (16KB)
    __shared__ int      hcnt[NWIN];     // histogram, then rank counter  (3.1KB)
    __shared__ int      hbase[NWIN];    // reserved global base          (3.1KB)

    int tid = threadIdx.x;
    int e0  = blockIdx.x * TILE;

    for (int w = tid; w < NWIN; w += 256) hcnt[w] = 0;
    __syncthreads();

    for (int i = tid; i < TILE; i += 256) {
        int e = e0 + i;
        if (e < E) {
            int d = dst[e];
            int s = src[e];
            int wid = d >> 7;                       // WN = 128
            int dl  = d & (WN - 1);
            se[i] = ((uint)s << 7) | (uint)dl;
            sw[i] = (ushort_t)wid;
            atomicAdd(&hcnt[wid], 1);
        } else {
            sw[i] = 0xFFFFu;
        }
    }
    __syncthreads();

    for (int w = tid; w < NWIN; w += 256) {
        int c = hcnt[w];
        hbase[w] = c ? atomicAdd(&tails[w], c) : 0;
        hcnt[w] = 0;                                // reuse as rank counter
    }
    __syncthreads();

    for (int i = tid; i < TILE; i += 256) {
        uint wid = sw[i];
        if (wid == 0xFFFFu) continue;
        int rank = atomicAdd(&hcnt[wid], 1);
        int pos  = hbase[wid] + rank;
        if (pos < WCAP) bins[(size_t)wid * WCAP + pos] = se[i];
    }
}

// Phase B: block w reads its window's contiguous bin (~2046 edges),
// accumulates per-(node,bucket) slots in LDS, compacts each node into a
// 112B unified row {norm f32, 4 uchar stored counts, <=52 ushort entries},
// writes rows + cnt4 coalesced (plain stores -> L2/L3 retained for agg).
__global__ __launch_bounds__(256) void build_window_kernel(const uint* __restrict__ bins,
                                                           const int* __restrict__ tails,
                                                           int* __restrict__ cnt4,
                                                           ushort_t* __restrict__ ellc) {
    __shared__ int lcnt[WN * NB];                            //  2048 B
    __shared__ ushort_t lell[WN * NB * BCAP];                // 24576 B
    __shared__ __align__(16) ushort_t lrow[WN * RS];         // 14336 B

    int w   = blockIdx.x;
    int tid = threadIdx.x;

    for (int i = tid; i < WN * NB; i += 256) lcnt[i] = 0;
    __syncthreads();

    int cnt = tails[w];
    if (cnt > WCAP) cnt = WCAP;
    const uint* bs = bins + (size_t)w * WCAP;
    for (int i = tid; i < cnt; i += 256) {
        uint u = bs[i];
        int dl = (int)(u & (WN - 1));
        int s  = (int)(u >> 7);
        int b = (s >= BW) + (s >= 2 * BW) + (s >= 3 * BW);
        int lidx = dl * NB + b;
        int cpos = atomicAdd(&lcnt[lidx], 1);
        if (cpos < BCAP) lell[lidx * BCAP + cpos] = (ushort_t)(s - b * BW);
    }
    __syncthreads();

    // compact: one thread per node
    if (tid < WN) {
        int node = w * WN + tid;
        ushort_t* r = lrow + tid * RS;
        if (node < N) {
            int c0 = lcnt[tid * NB + 0], c1 = lcnt[tid * NB + 1];
            int c2 = lcnt[tid * NB + 2], c3 = lcnt[tid * NB + 3];
            float dg = (float)(c0 + c1 + c2 + c3);
            float nm = 1.0f / sqrtf(fmaxf(dg, 1.0f));
            int rem = ECAP;
            int t0 = min(min(c0, BCAP), rem); rem -= t0;
            int t1 = min(min(c1, BCAP), rem); rem -= t1;
            int t2 = min(min(c2, BCAP), rem); rem -= t2;
            int t3 = min(min(c3, BCAP), rem);
            uint nmb = __float_as_uint(nm);
            r[0] = (ushort_t)(nmb & 0xFFFFu);
            r[1] = (ushort_t)(nmb >> 16);
            r[2] = (ushort_t)(t0 | (t1 << 8));
            r[3] = (ushort_t)(t2 | (t3 << 8));
            int o = 4;
            for (int j = 0; j < t0; ++j) r[o++] = lell[(tid * NB + 0) * BCAP + j];
            for (int j = 0; j < t1; ++j) r[o++] = lell[(tid * NB + 1) * BCAP + j];
            for (int j = 0; j < t2; ++j) r[o++] = lell[(tid * NB + 2) * BCAP + j];
            for (int j = 0; j < t3; ++j) r[o++] = lell[(tid * NB + 3) * BCAP + j];
            while (o < RS) r[o++] = 0;
        } else {
            for (int o = 0; o < RS; ++o) r[o] = 0;
        }
    }
    __syncthreads();

    int nbase = w * WN;
    for (int i = tid; i < WN * NB; i += 256) {
        if (nbase + i / NB < N) cnt4[(size_t)nbase * NB + i] = lcnt[i];
    }
    const uint4* l4 = (const uint4*)lrow;
    uint4* g4 = (uint4*)(ellc + (size_t)nbase * RS);
    for (int i = tid; i < WN * RV; i += 256)
        g4[i] = l4[i];
}

// scaled0 = feat*norm (bf16, node-major 96B rows) and h0s = 0.1*feat (bf16).
__global__ __launch_bounds__(256) void norm_scaled0_kernel(const int* __restrict__ cnt4,
                                                           const float4* __restrict__ feat,
                                                           uint4* __restrict__ sA,
                                                           uint4* __restrict__ h0s) {
    int t = blockIdx.x * 256 + threadIdx.x;
    if (t >= N * C8) return;
    int n = t / C8;
    int c = t - n * C8;
    int4 cc = *(const int4*)(cnt4 + n * NB);
    float dg = (float)(cc.x + cc.y + cc.z + cc.w);
    float nm = 1.0f / sqrtf(fmaxf(dg, 1.0f));
    float4 v0 = feat[n * D4 + c * 2];
    float4 v1 = feat[n * D4 + c * 2 + 1];
    uint4 o;
    o.x = pack_bf16x2(v0.x * nm, v0.y * nm);
    o.y = pack_bf16x2(v0.z * nm, v0.w * nm);
    o.z = pack_bf16x2(v1.x * nm, v1.y * nm);
    o.w = pack_bf16x2(v1.z * nm, v1.w * nm);
    sA[t] = o;
    uint4 h;
    h.x = pack_bf16x2(v0.x * 0.1f, v0.y * 0.1f);
    h.y = pack_bf16x2(v0.z * 0.1f, v0.w * 0.1f);
    h.z = pack_bf16x2(v1.x * 0.1f, v1.y * 0.1f);
    h.w = pack_bf16x2(v1.z * 0.1f, v1.w * 0.1f);
    h0s[t] = h;
}

// AGG v3 (plain loads/stores): block = 42 nodes x 6 chunks. Compact rows
// staged into LDS; indices read from LDS; norm from row header. Split
// predicated 8-deep gather chains per bucket.
template <bool LAST>
__global__ __launch_bounds__(256) void agg_kernel(const uint4* __restrict__ scaled_in,
                                                  const uint4* __restrict__ ellc4,
                                                  const uint4* __restrict__ h0s,
                                                  uint4* __restrict__ scaled_out,
                                                  float4* __restrict__ h_out) {
    __shared__ uint4 srow[ANB * RV];    // 42 rows x 112B = 4704 B

    int tid = threadIdx.x;
    int nb  = blockIdx.x * ANB;
    {
        size_t gbase = (size_t)nb * RV;
        for (int f = tid; f < ANB * RV; f += 256) {
            size_t g = gbase + f;
            if (g < (size_t)NPADR * RV) srow[f] = ellc4[g];
        }
    }
    __syncthreads();

    int ln = tid / C8;
    int c  = tid - ln * C8;
    int n  = nb + ln;
    if (tid >= ANB * C8 || n >= N) return;

    const uint*     su  = (const uint*)srow;
    const ushort_t* s16 = (const ushort_t*)srow;
    float nm = __uint_as_float(su[ln * RU]);
    uint  w1 = su[ln * RU + 1];
    int sc[NB] = {(int)(w1 & 255u), (int)((w1 >> 8) & 255u),
                  (int)((w1 >> 16) & 255u), (int)(w1 >> 24)};
    int ebase = ln * RS + 4;

    float a[8] = {0.f, 0.f, 0.f, 0.f, 0.f, 0.f, 0.f, 0.f};
    auto addv = [&](uint4 v) {
        unpack_add(v.x, a[0], a[1]); unpack_add(v.y, a[2], a[3]);
        unpack_add(v.z, a[4], a[5]); unpack_add(v.w, a[6], a[7]);
    };

    int o = 0;
#pragma unroll
    for (int p = 0; p < NB; ++p) {
        const uint4* base = scaled_in + (size_t)p * (BW * C8) + c;
        int cnt = sc[p];
        uint s8[8];
        uint4 v[8];
#pragma unroll
        for (int jj = 0; jj < 8; ++jj)
            if (jj < cnt) s8[jj] = s16[ebase + o + jj];
#pragma unroll
        for (int jj = 0; jj < 8; ++jj)
            if (jj < cnt) v[jj] = base[s8[jj] * C8];    // loads issue together
#pragma unroll
        for (int jj = 0; jj < 8; ++jj)
            if (jj < cnt) addv(v[jj]);
        for (int j = 8; j < cnt; ++j)                   // rare tail
            addv(base[s16[ebase + o + j] * C8]);
        o += cnt;
    }

    int t = n * C8 + c;
    uint4 hs = h0s[t];
    float rr[8] = {0.f, 0.f, 0.f, 0.f, 0.f, 0.f, 0.f, 0.f};
    unpack_add(hs.x, rr[0], rr[1]); unpack_add(hs.y, rr[2], rr[3]);
    unpack_add(hs.z, rr[4], rr[5]); unpack_add(hs.w, rr[6], rr[7]);
    float scn = 0.9f * nm;
    float hv[8];
#pragma unroll
    for (int k = 0; k < 8; ++k) hv[k] = fmaf(scn, a[k], rr[k]);
    if (LAST) {
        float4 o0 = {hv[0], hv[1], hv[2], hv[3]};
        float4 o1 = {hv[4], hv[5], hv[6], hv[7]};
        h_out[n * D4 + c * 2]     = o0;
        h_out[n * D4 + c * 2 + 1] = o1;
    } else {
        uint4 ov;
        ov.x = pack_bf16x2(hv[0] * nm, hv[1] * nm);
        ov.y = pack_bf16x2(hv[2] * nm, hv[3] * nm);
        ov.z = pack_bf16x2(hv[4] * nm, hv[5] * nm);
        ov.w = pack_bf16x2(hv[6] * nm, hv[7] * nm);
        scaled_out[t] = ov;
    }
}

// rst = relu(h@w1 + b1)@w2 + b2 + features.  (4 thr/node, weights in LDS:
// wave-uniform broadcast ds_read_b128, conflict-free.)
__global__ __launch_bounds__(256) void ffn_kernel(const float* __restrict__ r,
                                                  const float* __restrict__ feat,
                                                  const float* __restrict__ w1,
                                                  const float* __restrict__ b1,
                                                  const float* __restrict__ w2,
                                                  const float* __restrict__ b2,
                                                  float* __restrict__ rst) {
    __shared__ __align__(16) float sw1[D * D];   // 9216 B
    __shared__ __align__(16) float sw2[D * D];   // 9216 B
    __shared__ float sb[2 * D];                  //  384 B
    __shared__ float sh[FNB * HP];               // 12544 B

    int tid = threadIdx.x;
    for (int i = tid; i < D * D; i += 256) {
        sw1[i] = w1[i];
        sw2[i] = w2[i];
    }
    if (tid < D) {
        sb[tid] = b1[tid];
        sb[D + tid] = b2[tid];
    }

    int nb = blockIdx.x * FNB;
    const float4* r4 = (const float4*)r + (size_t)nb * D4;
    int maxf4 = (N - nb) * D4;
    if (maxf4 > FNB * D4) maxf4 = FNB * D4;
    for (int f = tid; f < maxf4; f += 256) {
        float4 v = r4[f];
        int row = f / D4;
        int col = (f - row * D4) * 4;
        float* dp = sh + row * HP + col;
        dp[0] = v.x; dp[1] = v.y; dp[2] = v.z; dp[3] = v.w;
    }
    __syncthreads();

    int n_local = tid & 63;
    int co = __builtin_amdgcn_readfirstlane((tid >> 6) * 12);   // wave-uniform
    int node = nb + n_local;
    bool alive = node < N;
    const float* hrow = sh + n_local * HP;

    float acc[12];
#pragma unroll
    for (int j = 0; j < 12; ++j) acc[j] = sb[co + j];
#pragma unroll
    for (int k = 0; k < D; ++k) {
        float hk = hrow[k];
        const float4* wr = (const float4*)(sw1 + k * D + co);
#pragma unroll
        for (int jc = 0; jc < 3; ++jc) {
            float4 wv = wr[jc];
            acc[4 * jc + 0] = fmaf(hk, wv.x, acc[4 * jc + 0]);
            acc[4 * jc + 1] = fmaf(hk, wv.y, acc[4 * jc + 1]);
            acc[4 * jc + 2] = fmaf(hk, wv.z, acc[4 * jc + 2]);
            acc[4 * jc + 3] = fmaf(hk, wv.w, acc[4 * jc + 3]);
        }
    }
#pragma unroll
    for (int j = 0; j < 12; ++j) acc[j] = fmaxf(acc[j], 0.0f);
    __syncthreads();
    {
        float* hw = sh + n_local * HP + co;
#pragma unroll
        for (int j = 0; j < 12; ++j) hw[j] = acc[j];
    }
    __syncthreads();
#pragma unroll
    for (int j = 0; j < 12; ++j) acc[j] = sb[D + co + j];
#pragma unroll
    for (int k = 0; k < D; ++k) {
        float hk = hrow[k];
        const float4* wr = (const float4*)(sw2 + k * D + co);
#pragma unroll
        for (int jc = 0; jc < 3; ++jc) {
            float4 wv = wr[jc];
            acc[4 * jc + 0] = fmaf(hk, wv.x, acc[4 * jc + 0]);
            acc[4 * jc + 1] = fmaf(hk, wv.y, acc[4 * jc + 1]);
            acc[4 * jc + 2] = fmaf(hk, wv.z, acc[4 * jc + 2]);
            acc[4 * jc + 3] = fmaf(hk, wv.w, acc[4 * jc + 3]);
        }
    }
    if (alive) {
        const float4* f4 = (const float4*)feat + (size_t)node * D4 + (co / 4);
        float4*       o4 = (float4*)rst + (size_t)node * D4 + (co / 4);
#pragma unroll
        for (int jc = 0; jc < 3; ++jc) {
            float4 fv = f4[jc];
            float4 o;
            o.x = acc[4 * jc + 0] + fv.x;
            o.y = acc[4 * jc + 1] + fv.y;
            o.z = acc[4 * jc + 2] + fv.z;
            o.w = acc[4 * jc + 3] + fv.w;
            o4[jc] = o;
        }
    }
}

extern "C" void kernel_launch(void* const* d_in, const int* in_sizes, int n_in,
                              void* d_out, int out_size, void* d_ws, size_t ws_size,
                              hipStream_t stream) {
    const float* feat = (const float*)d_in[0];
    const int*   src  = (const int*)d_in[1];
    const int*   dst  = (const int*)d_in[2];
    const float* w1   = (const float*)d_in[3];
    const float* b1   = (const float*)d_in[4];
    const float* w2   = (const float*)d_in[5];
    const float* b2   = (const float*)d_in[6];

    float* rst   = (float*)d_out;                  // output 0: [N, D]
    float* r_out = rst + (size_t)N * D;            // output 1: [N, D]

    // workspace layout (16B-aligned offsets), total ~42.0 MB
    char*     w     = (char*)d_ws;
    int*      cnt4  = (int*)w;                               //  1,600,000 B
    // gap: 400,000 B (reserved)
    ushort_t* ellc  = (ushort_t*)(w + 2000000);              // 11,210,752 B (NPADR*112)
    uint4*    sA    = (uint4*)(w + 2000000 + 11210752);      //  9,600,000 B
    uint4*    sB    = sA + (size_t)N * C8;                   //  9,600,000 B
    uint4*    h0s   = sB + (size_t)N * C8;                   //  9,600,000 B
    // build-phase scratch, dead before sA/sB are first written:
    uint*     bins  = (uint*)sA;                             //  8,007,680 B (aliases sA)
    int*      tails = (int*)sB;                              //      3,128 B (aliases sB)

    zero_kernel<<<(NWIN + 255) / 256, 256, 0, stream>>>(tails);
    bin_scan_kernel<<<(E + TILE - 1) / TILE, 256, 0, stream>>>(src, dst, bins, tails);
    build_window_kernel<<<NWIN, 256, 0, stream>>>(bins, tails, cnt4, ellc);
    norm_scaled0_kernel<<<(N * C8 + 255) / 256, 256, 0, stream>>>(
        cnt4, (const float4*)feat, sA, h0s);

    uint4* bufs[2] = {sA, sB};
    int agg_grid = (N + ANB - 1) / ANB;
    for (int hop = 0; hop < 10; ++hop) {
        const uint4* in  = bufs[hop & 1];
        uint4*       out = bufs[(hop + 1) & 1];
        if (hop < 9) {
            agg_kernel<false><<<agg_grid, 256, 0, stream>>>(
                in, (const uint4*)ellc, h0s, out, nullptr);
        } else {
            agg_kernel<true><<<agg_grid, 256, 0, stream>>>(
                in, (const uint4*)ellc, h0s, nullptr, (float4*)r_out);
        }
    }

    ffn_kernel<<<(N + FNB - 1) / FNB, 256, 0, stream>>>(
        r_out, feat, w1, b1, w2, b2, rst);
}